// Round 6
// baseline (454.330 us; speedup 1.0000x reference)
//
#include <hip/hip_runtime.h>
#include <math.h>

#define BB 2
#define CC_ 512
#define GG 32
#define CG 16
#define NN 4096
#define NCH 4
#define EPSF 1e-6f
#define SCALEF 0.04419417382415922f   // 1/sqrt(512)

typedef unsigned short ushort_t;
typedef __bf16 bf16x8 __attribute__((ext_vector_type(8)));
typedef ushort_t ushortx8 __attribute__((ext_vector_type(8)));
typedef float floatx4 __attribute__((ext_vector_type(4)));

__device__ __forceinline__ ushort_t f2bf(float f) {
    union { float f; unsigned u; } x; x.f = f;
    unsigned r = (x.u + 0x7FFFu + ((x.u >> 16) & 1u)) >> 16;   // RNE
    return (ushort_t)r;
}
__device__ __forceinline__ float bf2f(ushort_t v) {
    union { unsigned u; float f; } x; x.u = ((unsigned)v) << 16; return x.f;
}

// ---------------- weight prep: fp32 -> bf16, qkv packed [1536][512] ----------------
__global__ __launch_bounds__(256) void wprep(const float* __restrict__ wq,
                                             const float* __restrict__ wk,
                                             const float* __restrict__ wv,
                                             const float* __restrict__ wp,
                                             ushort_t* __restrict__ wqkv,
                                             ushort_t* __restrict__ wpb) {
    int idx4 = blockIdx.x * 256 + threadIdx.x;     // 4*65536 float4 total
    int m = idx4 >> 16;
    int r = idx4 & 65535;
    const float* src = (m == 0) ? wq : (m == 1) ? wk : (m == 2) ? wv : wp;
    float4 v = ((const float4*)src)[r];
    ushort4 u;
    u.x = f2bf(v.x); u.y = f2bf(v.y); u.z = f2bf(v.z); u.w = f2bf(v.w);
    if (m < 3) ((ushort4*)wqkv)[(size_t)m * 65536 + r] = u;
    else       ((ushort4*)wpb)[r] = u;
}

// ---------------- GroupNorm stats: one block per (b,g) ----------------
__global__ __launch_bounds__(256) void gn_stats(const float* __restrict__ x,
                                                float* __restrict__ mv) {
    int bg = blockIdx.x;
    const float4* xp = (const float4*)(x + (size_t)bg * (CG * NN));
    float s = 0.f, ss = 0.f;
    for (int idx = threadIdx.x; idx < CG * NN / 4; idx += 256) {
        float4 v = xp[idx];
        s  += (v.x + v.y) + (v.z + v.w);
        ss += v.x * v.x + v.y * v.y + v.z * v.z + v.w * v.w;
    }
    __shared__ float sm[8];
    for (int off = 32; off > 0; off >>= 1) {
        s  += __shfl_down(s, off, 64);
        ss += __shfl_down(ss, off, 64);
    }
    int lane = threadIdx.x & 63, wv = threadIdx.x >> 6;
    if (lane == 0) { sm[wv] = s; sm[4 + wv] = ss; }
    __syncthreads();
    if (threadIdx.x == 0) {
        s  = sm[0] + sm[1] + sm[2] + sm[3];
        ss = sm[4] + sm[5] + sm[6] + sm[7];
        const float inv = 1.0f / (float)(CG * NN);
        float mean = s * inv;
        float var  = ss * inv - mean * mean;
        mv[bg]      = mean;
        mv[64 + bg] = rsqrtf(var + EPSF);
    }
}

// ------------- GN apply + transpose: hT bf16 [B][N][C] -------------
__global__ __launch_bounds__(256) void gn_apply_t(const float* __restrict__ x,
                                                  const float* __restrict__ gamma,
                                                  const float* __restrict__ beta,
                                                  const float* __restrict__ mv,
                                                  ushort_t* __restrict__ hT) {
    const int b  = blockIdx.z;
    const int c0 = blockIdx.y * 64;
    const int n0 = blockIdx.x * 64;
    __shared__ float T[64][65];
    const int tid = threadIdx.x;
#pragma unroll
    for (int it = 0; it < 4; ++it) {
        int c  = it * 16 + (tid >> 4);
        int n4 = (tid & 15) * 4;
        int bg = b * 32 + ((c0 + c) >> 4);
        float a  = mv[64 + bg] * gamma[c0 + c];
        float b2 = beta[c0 + c] - mv[bg] * a;
        float4 v = *(const float4*)&x[((size_t)b * CC_ + c0 + c) * NN + n0 + n4];
        T[c][n4 + 0] = v.x * a + b2;
        T[c][n4 + 1] = v.y * a + b2;
        T[c][n4 + 2] = v.z * a + b2;
        T[c][n4 + 3] = v.w * a + b2;
    }
    __syncthreads();
#pragma unroll
    for (int it = 0; it < 4; ++it) {
        int n  = it * 16 + (tid >> 4);
        int c4 = (tid & 15) * 4;
        ushort4 u;
        u.x = f2bf(T[c4 + 0][n]); u.y = f2bf(T[c4 + 1][n]);
        u.z = f2bf(T[c4 + 2][n]); u.w = f2bf(T[c4 + 3][n]);
        *(ushort4*)&hT[((size_t)b * NN + n0 + n) * CC_ + c0 + c4] = u;
    }
}

// ---------------- fused QKV conv (MFMA): grid (64, 12) ----------------
// Staging: each thread loads TWO bf16x8 (16 elems) covering half*16..half*16+16.
__global__ __launch_bounds__(256) void conv_qkv(const ushort_t* __restrict__ hT,
                                                const ushort_t* __restrict__ wqkv,
                                                const float* __restrict__ bq,
                                                const float* __restrict__ bk,
                                                const float* __restrict__ bv,
                                                ushort_t* __restrict__ qT,
                                                ushort_t* __restrict__ kT,
                                                ushort_t* __restrict__ vB) {
    constexpr int ASTR = 40;
    __shared__ __align__(16) char smem[34816];   // max(2*128*40*2, 128*136*2)
    ushort_t* At = (ushort_t*)smem;
    ushort_t* Bt = At + 128 * ASTR;

    const int m0  = blockIdx.x * 128;            // global row (b*N+n)
    const int o0g = blockIdx.y * 128;            // 0..1535
    const int matid = o0g >> 9;
    const int o0 = o0g & 511;
    const int tid = threadIdx.x;
    const int w = tid >> 6, lane = tid & 63, quad = lane >> 4, n16 = lane & 15;
    const int wm = w & 1, wn = w >> 1;
    const int r2 = tid >> 1, half = tid & 1;

    floatx4 acc[4][4];
#pragma unroll
    for (int i = 0; i < 4; ++i)
#pragma unroll
        for (int j = 0; j < 4; ++j) acc[i][j] = (floatx4){0.f, 0.f, 0.f, 0.f};

    for (int k0 = 0; k0 < CC_; k0 += 32) {
        const ushort_t* asrc = &hT[(size_t)(m0 + r2) * CC_ + k0 + half * 16];
        bf16x8 a0 = *(const bf16x8*)(asrc);
        bf16x8 a1 = *(const bf16x8*)(asrc + 8);
        const ushort_t* wsrc = &wqkv[(size_t)(o0g + r2) * CC_ + k0 + half * 16];
        bf16x8 w0 = *(const bf16x8*)(wsrc);
        bf16x8 w1 = *(const bf16x8*)(wsrc + 8);
        __syncthreads();
        *(bf16x8*)&At[r2 * ASTR + half * 16]     = a0;
        *(bf16x8*)&At[r2 * ASTR + half * 16 + 8] = a1;
        *(bf16x8*)&Bt[r2 * ASTR + half * 16]     = w0;
        *(bf16x8*)&Bt[r2 * ASTR + half * 16 + 8] = w1;
        __syncthreads();
        bf16x8 af[4], bf_[4];
#pragma unroll
        for (int mt = 0; mt < 4; ++mt)
            af[mt] = *(const bf16x8*)&At[(wm * 64 + mt * 16 + n16) * ASTR + quad * 8];
#pragma unroll
        for (int nt = 0; nt < 4; ++nt)
            bf_[nt] = *(const bf16x8*)&Bt[(wn * 64 + nt * 16 + n16) * ASTR + quad * 8];
#pragma unroll
        for (int mt = 0; mt < 4; ++mt)
#pragma unroll
            for (int nt = 0; nt < 4; ++nt)
                acc[mt][nt] = __builtin_amdgcn_mfma_f32_16x16x32_bf16(af[mt], bf_[nt], acc[mt][nt], 0, 0, 0);
    }

    const float* bias = (matid == 0) ? bq : (matid == 1) ? bk : bv;
    float bsv[4];
#pragma unroll
    for (int nt = 0; nt < 4; ++nt) bsv[nt] = bias[o0 + wn * 64 + nt * 16 + n16];

    if (matid < 2) {
        float scale = (matid == 0) ? SCALEF : 1.0f;
        ushort_t* dst = (matid == 0) ? qT : kT;
#pragma unroll
        for (int mt = 0; mt < 4; ++mt)
#pragma unroll
            for (int nt = 0; nt < 4; ++nt) {
                int o = o0 + wn * 64 + nt * 16 + n16;
#pragma unroll
                for (int r = 0; r < 4; ++r) {
                    int m = m0 + wm * 64 + mt * 16 + quad * 4 + r;
                    dst[(size_t)m * CC_ + o] = f2bf((acc[mt][nt][r] + bsv[nt]) * scale);
                }
            }
    } else {
        __syncthreads();
        ushort_t* T = (ushort_t*)smem;           // [128 o][136]
#pragma unroll
        for (int mt = 0; mt < 4; ++mt)
#pragma unroll
            for (int nt = 0; nt < 4; ++nt) {
                int ol = wn * 64 + nt * 16 + n16;
#pragma unroll
                for (int r = 0; r < 4; ++r) {
                    int nl = wm * 64 + mt * 16 + quad * 4 + r;
                    T[ol * 136 + nl] = f2bf(acc[mt][nt][r] + bsv[nt]);
                }
            }
        __syncthreads();
        const int bb = m0 >> 12;
        const int n0 = m0 & (NN - 1);
#pragma unroll
        for (int i = 0; i < 8; ++i) {
            ushortx8 v = *(const ushortx8*)&T[r2 * 136 + half * 64 + i * 8];
            *(ushortx8*)&vB[((size_t)bb * CC_ + o0 + r2) * NN + n0 + half * 64 + i * 8] = v;
        }
    }
}

// ---------------- MFMA flash attention v3: 32q blocks, 32-key tiles ----------------
// qT,kT bf16 [B][N][C] (q pre-scaled); vB bf16 [B][C][N].
// opart bf16 [B][NCH][C][N]; lpart fp32 [B][NCH][2][N].
// Block: 256 thr = 4 waves. Wave w: QK on (qt=w&1 -> 16q) x (kh=w>>1 -> 16 keys);
// PV on all 32q x 128-ch slice (cb=w*128).
__global__ __launch_bounds__(256, 3) void flash_attn3(
        const ushort_t* __restrict__ qT, const ushort_t* __restrict__ kT,
        const ushort_t* __restrict__ vB,
        ushort_t* __restrict__ opart, float* __restrict__ lpart) {
    const int b     = blockIdx.z;
    const int chunk = blockIdx.y;
    const int i0    = blockIdx.x * 32;
    const ushort_t* qTb = qT + (size_t)b * NN * CC_;
    const ushort_t* kTb = kT + (size_t)b * NN * CC_;
    const ushort_t* vBb = vB + (size_t)b * CC_ * NN;

    __shared__ ushort_t Klds[32 * 520];   // 33.3 KB
    __shared__ ushort_t Plds[32 * 40];    // 2.5 KB

    const int tid  = threadIdx.x;
    const int w    = tid >> 6;
    const int lane = tid & 63;
    const int quad = lane >> 4;
    const int n16  = lane & 15;
    const int qt   = w & 1;
    const int kh   = w >> 1;
    const int cb   = w * 128;

    bf16x8 aq[16];
    {
        const ushort_t* qrow = qTb + (size_t)(i0 + qt * 16 + n16) * CC_ + quad * 8;
#pragma unroll
        for (int ks = 0; ks < 16; ++ks) aq[ks] = *(const bf16x8*)(qrow + ks * 32);
    }

    floatx4 acc[2][8];
#pragma unroll
    for (int mt = 0; mt < 2; ++mt)
#pragma unroll
        for (int st = 0; st < 8; ++st) acc[mt][st] = (floatx4){0.f, 0.f, 0.f, 0.f};
    float lsum[4] = {0.f, 0.f, 0.f, 0.f};

    const int jbase = chunk * (NN / NCH);
    for (int t = 0; t < (NN / NCH) / 32; ++t) {
        const int j0 = jbase + t * 32;
#pragma unroll
        for (int it = 0; it < 8; ++it) {
            int row = w * 8 + it;
            __builtin_amdgcn_global_load_lds(
                (const __attribute__((address_space(1))) unsigned int*)
                    (kTb + (size_t)(j0 + row) * CC_ + lane * 8),
                (__attribute__((address_space(3))) unsigned int*)(&Klds[row * 520]),
                16, 0, 0);
        }
        __syncthreads();

        // QK^T: 16q (qt) x 16 keys (kh), two independent chains
        floatx4 sa = (floatx4){0.f, 0.f, 0.f, 0.f};
        floatx4 sb = (floatx4){0.f, 0.f, 0.f, 0.f};
        const ushort_t* kb = &Klds[(kh * 16 + n16) * 520 + quad * 8];
#pragma unroll
        for (int ks = 0; ks < 8; ++ks) {
            bf16x8 k0 = *(const bf16x8*)(kb + (2 * ks) * 32);
            bf16x8 k1 = *(const bf16x8*)(kb + (2 * ks + 1) * 32);
            sa = __builtin_amdgcn_mfma_f32_16x16x32_bf16(aq[2 * ks],     k0, sa, 0, 0, 0);
            sb = __builtin_amdgcn_mfma_f32_16x16x32_bf16(aq[2 * ks + 1], k1, sb, 0, 0, 0);
        }
        float e0 = __expf(sa[0] + sb[0]), e1 = __expf(sa[1] + sb[1]);
        float e2 = __expf(sa[2] + sb[2]), e3 = __expf(sa[3] + sb[3]);
        {
            float p0 = e0, p1 = e1, p2 = e2, p3 = e3;
            p0 += __shfl_xor(p0, 1); p1 += __shfl_xor(p1, 1);
            p2 += __shfl_xor(p2, 1); p3 += __shfl_xor(p3, 1);
            p0 += __shfl_xor(p0, 2); p1 += __shfl_xor(p1, 2);
            p2 += __shfl_xor(p2, 2); p3 += __shfl_xor(p3, 2);
            p0 += __shfl_xor(p0, 4); p1 += __shfl_xor(p1, 4);
            p2 += __shfl_xor(p2, 4); p3 += __shfl_xor(p3, 4);
            p0 += __shfl_xor(p0, 8); p1 += __shfl_xor(p1, 8);
            p2 += __shfl_xor(p2, 8); p3 += __shfl_xor(p3, 8);
            lsum[0] += p0; lsum[1] += p1; lsum[2] += p2; lsum[3] += p3;
        }
        const int pr = qt * 16 + quad * 4;
        Plds[(pr + 0) * 40 + kh * 16 + n16] = f2bf(e0);
        Plds[(pr + 1) * 40 + kh * 16 + n16] = f2bf(e1);
        Plds[(pr + 2) * 40 + kh * 16 + n16] = f2bf(e2);
        Plds[(pr + 3) * 40 + kh * 16 + n16] = f2bf(e3);
        __syncthreads();

        // PV: 32q x 128-ch slice; K=32 covers the whole key tile in one MFMA
        bf16x8 ap0 = *(const bf16x8*)&Plds[n16 * 40 + quad * 8];
        bf16x8 ap1 = *(const bf16x8*)&Plds[(16 + n16) * 40 + quad * 8];
#pragma unroll
        for (int st = 0; st < 8; ++st) {
            bf16x8 bv8 = *(const bf16x8*)(vBb + (size_t)(cb + st * 16 + n16) * NN + j0 + quad * 8);
            acc[0][st] = __builtin_amdgcn_mfma_f32_16x16x32_bf16(ap0, bv8, acc[0][st], 0, 0, 0);
            acc[1][st] = __builtin_amdgcn_mfma_f32_16x16x32_bf16(ap1, bv8, acc[1][st], 0, 0, 0);
        }
    }

    if (n16 == 0) {
        float* lp = lpart + (((size_t)b * NCH + chunk) * 2 + kh) * NN + i0 + qt * 16 + quad * 4;
        lp[0] = lsum[0]; lp[1] = lsum[1]; lp[2] = lsum[2]; lp[3] = lsum[3];
    }
    ushort_t* opb = opart + ((size_t)b * NCH + chunk) * CC_ * NN;
#pragma unroll
    for (int mt = 0; mt < 2; ++mt)
#pragma unroll
        for (int st = 0; st < 8; ++st) {
            int c = cb + st * 16 + n16;
            int n = i0 + mt * 16 + quad * 4;
            ushort4 u;
            u.x = f2bf(acc[mt][st][0]); u.y = f2bf(acc[mt][st][1]);
            u.z = f2bf(acc[mt][st][2]); u.w = f2bf(acc[mt][st][3]);
            *(ushort4*)&opb[(size_t)c * NN + n] = u;
        }
}

// ------------- combine partials -> attnT bf16 [B][N][C] -------------
__global__ __launch_bounds__(256) void combine(const ushort_t* __restrict__ opart,
                                               const float* __restrict__ lpart,
                                               ushort_t* __restrict__ attnT) {
    const int b  = blockIdx.z;
    const int c0 = blockIdx.y * 64;
    const int n0 = blockIdx.x * 64;
    __shared__ float S[64][65];
    const int tid = threadIdx.x;
#pragma unroll
    for (int it = 0; it < 4; ++it) {
        int c  = it * 16 + (tid >> 4);
        int n4 = (tid & 15) * 4;
        float s0 = 0.f, s1 = 0.f, s2 = 0.f, s3 = 0.f;
#pragma unroll
        for (int k = 0; k < NCH; ++k) {
            ushort4 u = *(const ushort4*)&opart[(((size_t)b * NCH + k) * CC_ + c0 + c) * NN + n0 + n4];
            s0 += bf2f(u.x); s1 += bf2f(u.y); s2 += bf2f(u.z); s3 += bf2f(u.w);
        }
        S[c][n4 + 0] = s0; S[c][n4 + 1] = s1; S[c][n4 + 2] = s2; S[c][n4 + 3] = s3;
    }
    __syncthreads();
#pragma unroll
    for (int it = 0; it < 4; ++it) {
        int n  = it * 16 + (tid >> 4);
        int c4 = (tid & 15) * 4;
        float l = 0.f;
#pragma unroll
        for (int k = 0; k < NCH * 2; ++k)
            l += lpart[(((size_t)b * NCH) * 2 + k) * NN + n0 + n];
        float linv = 1.0f / l;
        ushort4 u;
        u.x = f2bf(S[c4 + 0][n] * linv); u.y = f2bf(S[c4 + 1][n] * linv);
        u.z = f2bf(S[c4 + 2][n] * linv); u.w = f2bf(S[c4 + 3][n] * linv);
        *(ushort4*)&attnT[((size_t)b * NN + n0 + n) * CC_ + c0 + c4] = u;
    }
}

// ---------------- proj conv (MFMA): tile 128m x 64o, grid (64, 8) ----------------
__global__ __launch_bounds__(256) void conv_proj(const ushort_t* __restrict__ attnT,
                                                 const ushort_t* __restrict__ wpb,
                                                 const float* __restrict__ bp,
                                                 const float* __restrict__ x,
                                                 float* __restrict__ out) {
    constexpr int ASTR = 40;
    __shared__ __align__(16) char smem[33792];   // max((128+64)*40*2, 64*132*4)
    ushort_t* At = (ushort_t*)smem;              // [128 m][40]
    ushort_t* Bt = At + 128 * ASTR;              // [64 o][40]

    const int m0 = blockIdx.x * 128;
    const int o0 = blockIdx.y * 64;
    const int tid = threadIdx.x;
    const int w = tid >> 6, lane = tid & 63, quad = lane >> 4, n16 = lane & 15;
    const int wm = w & 1, wn = w >> 1;
    const int r2 = tid >> 1, half = tid & 1;

    floatx4 acc[4][2];
#pragma unroll
    for (int i = 0; i < 4; ++i)
#pragma unroll
        for (int j = 0; j < 2; ++j) acc[i][j] = (floatx4){0.f, 0.f, 0.f, 0.f};

    for (int k0 = 0; k0 < CC_; k0 += 32) {
        const ushort_t* asrc = &attnT[(size_t)(m0 + r2) * CC_ + k0 + half * 16];
        bf16x8 a0 = *(const bf16x8*)(asrc);
        bf16x8 a1 = *(const bf16x8*)(asrc + 8);
        bf16x8 w0, w1;
        if (tid < 128) {
            const ushort_t* wsrc = &wpb[(size_t)(o0 + r2) * CC_ + k0 + half * 16];
            w0 = *(const bf16x8*)(wsrc);
            w1 = *(const bf16x8*)(wsrc + 8);
        }
        __syncthreads();
        *(bf16x8*)&At[r2 * ASTR + half * 16]     = a0;
        *(bf16x8*)&At[r2 * ASTR + half * 16 + 8] = a1;
        if (tid < 128) {
            *(bf16x8*)&Bt[r2 * ASTR + half * 16]     = w0;
            *(bf16x8*)&Bt[r2 * ASTR + half * 16 + 8] = w1;
        }
        __syncthreads();
        bf16x8 af[4], bf_[2];
#pragma unroll
        for (int mt = 0; mt < 4; ++mt)
            af[mt] = *(const bf16x8*)&At[(wm * 64 + mt * 16 + n16) * ASTR + quad * 8];
#pragma unroll
        for (int nt = 0; nt < 2; ++nt)
            bf_[nt] = *(const bf16x8*)&Bt[(wn * 32 + nt * 16 + n16) * ASTR + quad * 8];
#pragma unroll
        for (int mt = 0; mt < 4; ++mt)
#pragma unroll
            for (int nt = 0; nt < 2; ++nt)
                acc[mt][nt] = __builtin_amdgcn_mfma_f32_16x16x32_bf16(af[mt], bf_[nt], acc[mt][nt], 0, 0, 0);
    }

    float bsv[2];
#pragma unroll
    for (int nt = 0; nt < 2; ++nt) bsv[nt] = bp[o0 + wn * 32 + nt * 16 + n16];

    __syncthreads();
    float* Tf = (float*)smem;                    // [64 o][132]
#pragma unroll
    for (int mt = 0; mt < 4; ++mt)
#pragma unroll
        for (int nt = 0; nt < 2; ++nt) {
            int ol = wn * 32 + nt * 16 + n16;
#pragma unroll
            for (int r = 0; r < 4; ++r) {
                int nl = wm * 64 + mt * 16 + quad * 4 + r;
                Tf[ol * 132 + nl] = acc[mt][nt][r] + bsv[nt];
            }
        }
    __syncthreads();
    const int bb = m0 >> 12;
    const int n0 = m0 & (NN - 1);
    const int ro = tid >> 2;                     // 0..63
    const int cc = (tid & 3) * 32;
    const size_t obase = ((size_t)bb * CC_ + o0 + ro) * NN + n0 + cc;
#pragma unroll
    for (int i = 0; i < 8; ++i) {
        float4 v  = *(const float4*)&Tf[ro * 132 + cc + i * 4];
        float4 x4 = *(const float4*)&x[obase + i * 4];
        v.x += x4.x; v.y += x4.y; v.z += x4.z; v.w += x4.w;
        *(float4*)&out[obase + i * 4] = v;
    }
}

extern "C" void kernel_launch(void* const* d_in, const int* in_sizes, int n_in,
                              void* d_out, int out_size, void* d_ws, size_t ws_size,
                              hipStream_t stream) {
    const float* x        = (const float*)d_in[0];
    const float* gn_scale = (const float*)d_in[1];
    const float* gn_bias  = (const float*)d_in[2];
    const float* wq = (const float*)d_in[3];
    const float* bq = (const float*)d_in[4];
    const float* wk = (const float*)d_in[5];
    const float* bk = (const float*)d_in[6];
    const float* wv = (const float*)d_in[7];
    const float* bv = (const float*)d_in[8];
    const float* wp = (const float*)d_in[9];
    const float* bp = (const float*)d_in[10];
    float* outp = (float*)d_out;

    const size_t TENS = (size_t)BB * CC_ * NN;       // 4,194,304 elements
    ushort_t* hT    = (ushort_t*)d_ws;               // bf16 [B][N][C]
    ushort_t* qT    = hT    + TENS;
    ushort_t* kT    = qT    + TENS;
    ushort_t* vB    = kT    + TENS;                  // bf16 [B][C][N]
    ushort_t* attnT = vB    + TENS;                  // bf16 [B][N][C]
    ushort_t* opart = attnT + TENS;                  // bf16 [B][NCH][C][N]
    ushort_t* wqkv  = opart + (size_t)NCH * TENS;    // bf16 [1536][512]
    ushort_t* wpb   = wqkv  + (size_t)1536 * 512;    // bf16 [512][512]
    float*    lpart = (float*)(wpb + (size_t)512 * 512);  // [B][NCH][2][NN]
    float*    mv    = lpart + (size_t)BB * NCH * 2 * NN;  // 128 floats

    wprep<<<1024, 256, 0, stream>>>(wq, wk, wv, wp, wqkv, wpb);
    gn_stats<<<BB * GG, 256, 0, stream>>>(x, mv);
    gn_apply_t<<<dim3(NN / 64, CC_ / 64, BB), 256, 0, stream>>>(x, gn_scale, gn_bias, mv, hT);

    conv_qkv<<<dim3(BB * NN / 128, 1536 / 128), 256, 0, stream>>>(
        hT, wqkv, bq, bk, bv, qT, kT, vB);

    flash_attn3<<<dim3(NN / 32, NCH, BB), 256, 0, stream>>>(qT, kT, vB, opart, lpart);
    combine<<<dim3(NN / 64, CC_ / 64, BB), 256, 0, stream>>>(opart, lpart, attnT);

    conv_proj<<<dim3(BB * NN / 128, CC_ / 64), 256, 0, stream>>>(attnT, wpb, bp, x, outp);
}

// Round 7
// 290.073 us; speedup vs baseline: 1.5663x; 1.5663x over previous
//
#include <hip/hip_runtime.h>
#include <math.h>

#define BB 2
#define CC_ 512
#define GG 32
#define CG 16
#define NN 4096
#define NCH 4
#define EPSF 1e-6f
#define SCALEF 0.04419417382415922f   // 1/sqrt(512)

typedef unsigned short ushort_t;
typedef __bf16 bf16x8 __attribute__((ext_vector_type(8)));
typedef ushort_t ushortx8 __attribute__((ext_vector_type(8)));
typedef float floatx4 __attribute__((ext_vector_type(4)));

__device__ __forceinline__ ushort_t f2bf(float f) {
    union { float f; unsigned u; } x; x.f = f;
    unsigned r = (x.u + 0x7FFFu + ((x.u >> 16) & 1u)) >> 16;   // RNE
    return (ushort_t)r;
}
__device__ __forceinline__ float bf2f(ushort_t v) {
    union { unsigned u; float f; } x; x.u = ((unsigned)v) << 16; return x.f;
}

// ---------------- weight prep: fp32 -> bf16, qkv packed [1536][512] ----------------
__global__ __launch_bounds__(256) void wprep(const float* __restrict__ wq,
                                             const float* __restrict__ wk,
                                             const float* __restrict__ wv,
                                             const float* __restrict__ wp,
                                             ushort_t* __restrict__ wqkv,
                                             ushort_t* __restrict__ wpb) {
    int idx4 = blockIdx.x * 256 + threadIdx.x;     // 4*65536 float4 total
    int m = idx4 >> 16;
    int r = idx4 & 65535;
    const float* src = (m == 0) ? wq : (m == 1) ? wk : (m == 2) ? wv : wp;
    float4 v = ((const float4*)src)[r];
    ushort4 u;
    u.x = f2bf(v.x); u.y = f2bf(v.y); u.z = f2bf(v.z); u.w = f2bf(v.w);
    if (m < 3) ((ushort4*)wqkv)[(size_t)m * 65536 + r] = u;
    else       ((ushort4*)wpb)[r] = u;
}

// ---------------- GroupNorm stats: one block per (b,g) ----------------
__global__ __launch_bounds__(256) void gn_stats(const float* __restrict__ x,
                                                float* __restrict__ mv) {
    int bg = blockIdx.x;
    const float4* xp = (const float4*)(x + (size_t)bg * (CG * NN));
    float s = 0.f, ss = 0.f;
    for (int idx = threadIdx.x; idx < CG * NN / 4; idx += 256) {
        float4 v = xp[idx];
        s  += (v.x + v.y) + (v.z + v.w);
        ss += v.x * v.x + v.y * v.y + v.z * v.z + v.w * v.w;
    }
    __shared__ float sm[8];
    for (int off = 32; off > 0; off >>= 1) {
        s  += __shfl_down(s, off, 64);
        ss += __shfl_down(ss, off, 64);
    }
    int lane = threadIdx.x & 63, wv = threadIdx.x >> 6;
    if (lane == 0) { sm[wv] = s; sm[4 + wv] = ss; }
    __syncthreads();
    if (threadIdx.x == 0) {
        s  = sm[0] + sm[1] + sm[2] + sm[3];
        ss = sm[4] + sm[5] + sm[6] + sm[7];
        const float inv = 1.0f / (float)(CG * NN);
        float mean = s * inv;
        float var  = ss * inv - mean * mean;
        mv[bg]      = mean;
        mv[64 + bg] = rsqrtf(var + EPSF);
    }
}

// ------------- GN apply + transpose: hT bf16 [B][N][C] -------------
__global__ __launch_bounds__(256) void gn_apply_t(const float* __restrict__ x,
                                                  const float* __restrict__ gamma,
                                                  const float* __restrict__ beta,
                                                  const float* __restrict__ mv,
                                                  ushort_t* __restrict__ hT) {
    const int b  = blockIdx.z;
    const int c0 = blockIdx.y * 64;
    const int n0 = blockIdx.x * 64;
    __shared__ float T[64][65];
    const int tid = threadIdx.x;
#pragma unroll
    for (int it = 0; it < 4; ++it) {
        int c  = it * 16 + (tid >> 4);
        int n4 = (tid & 15) * 4;
        int bg = b * 32 + ((c0 + c) >> 4);
        float a  = mv[64 + bg] * gamma[c0 + c];
        float b2 = beta[c0 + c] - mv[bg] * a;
        float4 v = *(const float4*)&x[((size_t)b * CC_ + c0 + c) * NN + n0 + n4];
        T[c][n4 + 0] = v.x * a + b2;
        T[c][n4 + 1] = v.y * a + b2;
        T[c][n4 + 2] = v.z * a + b2;
        T[c][n4 + 3] = v.w * a + b2;
    }
    __syncthreads();
#pragma unroll
    for (int it = 0; it < 4; ++it) {
        int n  = it * 16 + (tid >> 4);
        int c4 = (tid & 15) * 4;
        ushort4 u;
        u.x = f2bf(T[c4 + 0][n]); u.y = f2bf(T[c4 + 1][n]);
        u.z = f2bf(T[c4 + 2][n]); u.w = f2bf(T[c4 + 3][n]);
        *(ushort4*)&hT[((size_t)b * NN + n0 + n) * CC_ + c0 + c4] = u;
    }
}

// ---------------- fused QKV conv (MFMA): grid (64, 12) — R6-proven ----------------
__global__ __launch_bounds__(256) void conv_qkv(const ushort_t* __restrict__ hT,
                                                const ushort_t* __restrict__ wqkv,
                                                const float* __restrict__ bq,
                                                const float* __restrict__ bk,
                                                const float* __restrict__ bv,
                                                ushort_t* __restrict__ qT,
                                                ushort_t* __restrict__ kT,
                                                ushort_t* __restrict__ vB) {
    constexpr int ASTR = 40;
    __shared__ __align__(16) char smem[34816];   // max(2*128*40*2, 128*136*2)
    ushort_t* At = (ushort_t*)smem;
    ushort_t* Bt = At + 128 * ASTR;

    const int m0  = blockIdx.x * 128;            // global row (b*N+n)
    const int o0g = blockIdx.y * 128;            // 0..1535
    const int matid = o0g >> 9;
    const int o0 = o0g & 511;
    const int tid = threadIdx.x;
    const int w = tid >> 6, lane = tid & 63, quad = lane >> 4, n16 = lane & 15;
    const int wm = w & 1, wn = w >> 1;
    const int r2 = tid >> 1, half = tid & 1;

    floatx4 acc[4][4];
#pragma unroll
    for (int i = 0; i < 4; ++i)
#pragma unroll
        for (int j = 0; j < 4; ++j) acc[i][j] = (floatx4){0.f, 0.f, 0.f, 0.f};

    for (int k0 = 0; k0 < CC_; k0 += 32) {
        const ushort_t* asrc = &hT[(size_t)(m0 + r2) * CC_ + k0 + half * 16];
        bf16x8 a0 = *(const bf16x8*)(asrc);
        bf16x8 a1 = *(const bf16x8*)(asrc + 8);
        const ushort_t* wsrc = &wqkv[(size_t)(o0g + r2) * CC_ + k0 + half * 16];
        bf16x8 w0 = *(const bf16x8*)(wsrc);
        bf16x8 w1 = *(const bf16x8*)(wsrc + 8);
        __syncthreads();
        *(bf16x8*)&At[r2 * ASTR + half * 16]     = a0;
        *(bf16x8*)&At[r2 * ASTR + half * 16 + 8] = a1;
        *(bf16x8*)&Bt[r2 * ASTR + half * 16]     = w0;
        *(bf16x8*)&Bt[r2 * ASTR + half * 16 + 8] = w1;
        __syncthreads();
        bf16x8 af[4], bf_[4];
#pragma unroll
        for (int mt = 0; mt < 4; ++mt)
            af[mt] = *(const bf16x8*)&At[(wm * 64 + mt * 16 + n16) * ASTR + quad * 8];
#pragma unroll
        for (int nt = 0; nt < 4; ++nt)
            bf_[nt] = *(const bf16x8*)&Bt[(wn * 64 + nt * 16 + n16) * ASTR + quad * 8];
#pragma unroll
        for (int mt = 0; mt < 4; ++mt)
#pragma unroll
            for (int nt = 0; nt < 4; ++nt)
                acc[mt][nt] = __builtin_amdgcn_mfma_f32_16x16x32_bf16(af[mt], bf_[nt], acc[mt][nt], 0, 0, 0);
    }

    const float* bias = (matid == 0) ? bq : (matid == 1) ? bk : bv;
    float bsv[4];
#pragma unroll
    for (int nt = 0; nt < 4; ++nt) bsv[nt] = bias[o0 + wn * 64 + nt * 16 + n16];

    if (matid < 2) {
        float scale = (matid == 0) ? SCALEF : 1.0f;
        ushort_t* dst = (matid == 0) ? qT : kT;
#pragma unroll
        for (int mt = 0; mt < 4; ++mt)
#pragma unroll
            for (int nt = 0; nt < 4; ++nt) {
                int o = o0 + wn * 64 + nt * 16 + n16;
#pragma unroll
                for (int r = 0; r < 4; ++r) {
                    int m = m0 + wm * 64 + mt * 16 + quad * 4 + r;
                    dst[(size_t)m * CC_ + o] = f2bf((acc[mt][nt][r] + bsv[nt]) * scale);
                }
            }
    } else {
        __syncthreads();
        ushort_t* T = (ushort_t*)smem;           // [128 o][136]
#pragma unroll
        for (int mt = 0; mt < 4; ++mt)
#pragma unroll
            for (int nt = 0; nt < 4; ++nt) {
                int ol = wn * 64 + nt * 16 + n16;
#pragma unroll
                for (int r = 0; r < 4; ++r) {
                    int nl = wm * 64 + mt * 16 + quad * 4 + r;
                    T[ol * 136 + nl] = f2bf(acc[mt][nt][r] + bsv[nt]);
                }
            }
        __syncthreads();
        const int bb = m0 >> 12;
        const int n0 = m0 & (NN - 1);
#pragma unroll
        for (int i = 0; i < 8; ++i) {
            ushortx8 v = *(const ushortx8*)&T[r2 * 136 + half * 64 + i * 8];
            *(ushortx8*)&vB[((size_t)bb * CC_ + o0 + r2) * NN + n0 + half * 64 + i * 8] = v;
        }
    }
}

// ---------------- MFMA flash attention v4: R3 partition + double-buffered K pipeline ----
// qT,kT bf16 [B][N][C] (q pre-scaled); vB bf16 [B][C][N].
// opart bf16 [B][NCH][C][N]; lpart fp32 [B][NCH][N].
// Block: 512 thr = 8 waves, 128 queries, 1024-key chunk, 64-key tiles.
// Pipeline: V[t] loads issued after top barrier (ride under QK+softmax);
// K[t+1] global_load_lds issued after mid barrier into alternate buffer
// (rides under PV, drained exactly at next top barrier).
__global__ __launch_bounds__(512, 2) void flash_attn4(
        const ushort_t* __restrict__ qT, const ushort_t* __restrict__ kT,
        const ushort_t* __restrict__ vB,
        ushort_t* __restrict__ opart, float* __restrict__ lpart) {
    const int b     = blockIdx.z;
    const int chunk = blockIdx.y;
    const int i0    = blockIdx.x * 128;
    const ushort_t* qTb = qT + (size_t)b * NN * CC_;
    const ushort_t* kTb = kT + (size_t)b * NN * CC_;
    const ushort_t* vBb = vB + (size_t)b * CC_ * NN;

    __shared__ ushort_t Klds[2][64 * 520];   // 2 x 66.6 KB
    __shared__ ushort_t Plds[128 * 72];      // 18.4 KB

    const int tid  = threadIdx.x;
    const int w    = tid >> 6;
    const int lane = tid & 63;
    const int quad = lane >> 4;
    const int n16  = lane & 15;
    const int cb   = w * 64;

    bf16x8 aq[16];
    {
        const ushort_t* qrow = qTb + (size_t)(i0 + w * 16 + n16) * CC_ + quad * 8;
#pragma unroll
        for (int ks = 0; ks < 16; ++ks) aq[ks] = *(const bf16x8*)(qrow + ks * 32);
    }

    floatx4 acc[8][4];
#pragma unroll
    for (int mt = 0; mt < 8; ++mt)
#pragma unroll
        for (int st = 0; st < 4; ++st) acc[mt][st] = (floatx4){0.f, 0.f, 0.f, 0.f};
    float lsum[4] = {0.f, 0.f, 0.f, 0.f};

    const int jbase = chunk * (NN / NCH);
    constexpr int NT = (NN / NCH) / 64;      // 16 tiles

    // prefetch tile 0 into buffer 0
#pragma unroll
    for (int it = 0; it < 8; ++it) {
        int row = w * 8 + it;
        __builtin_amdgcn_global_load_lds(
            (const __attribute__((address_space(1))) unsigned int*)
                (kTb + (size_t)(jbase + row) * CC_ + lane * 8),
            (__attribute__((address_space(3))) unsigned int*)(&Klds[0][row * 520]),
            16, 0, 0);
    }

    for (int t = 0; t < NT; ++t) {
        const int j0 = jbase + t * 64;
        const ushort_t* Kbuf = Klds[t & 1];
        __syncthreads();                     // K[t] arrived; Plds free from t-1

        // V[t] loads — issue early, consumed after mid barrier
        bf16x8 bv0[4], bv1[4];
#pragma unroll
        for (int st = 0; st < 4; ++st) {
            const ushort_t* vp = vBb + (size_t)(cb + st * 16 + n16) * NN + j0 + quad * 8;
            bv0[st] = *(const bf16x8*)(vp);
            bv1[st] = *(const bf16x8*)(vp + 32);
        }

        // QK^T: wave's 16 queries x 64 keys (4 j-strips), softmax, P -> LDS
#pragma unroll
        for (int js = 0; js < 4; ++js) {
            floatx4 s = (floatx4){0.f, 0.f, 0.f, 0.f};
            const ushort_t* kb = &Kbuf[(js * 16 + n16) * 520 + quad * 8];
#pragma unroll
            for (int ks = 0; ks < 16; ++ks) {
                bf16x8 bk = *(const bf16x8*)(kb + ks * 32);
                s = __builtin_amdgcn_mfma_f32_16x16x32_bf16(aq[ks], bk, s, 0, 0, 0);
            }
            float e0 = __expf(s[0]), e1 = __expf(s[1]);
            float e2 = __expf(s[2]), e3 = __expf(s[3]);
            float p0 = e0, p1 = e1, p2 = e2, p3 = e3;
            p0 += __shfl_xor(p0, 1); p1 += __shfl_xor(p1, 1);
            p2 += __shfl_xor(p2, 1); p3 += __shfl_xor(p3, 1);
            p0 += __shfl_xor(p0, 2); p1 += __shfl_xor(p1, 2);
            p2 += __shfl_xor(p2, 2); p3 += __shfl_xor(p3, 2);
            p0 += __shfl_xor(p0, 4); p1 += __shfl_xor(p1, 4);
            p2 += __shfl_xor(p2, 4); p3 += __shfl_xor(p3, 4);
            p0 += __shfl_xor(p0, 8); p1 += __shfl_xor(p1, 8);
            p2 += __shfl_xor(p2, 8); p3 += __shfl_xor(p3, 8);
            lsum[0] += p0; lsum[1] += p1; lsum[2] += p2; lsum[3] += p3;
            const int pr = w * 16 + quad * 4;
            Plds[(pr + 0) * 72 + js * 16 + n16] = f2bf(e0);
            Plds[(pr + 1) * 72 + js * 16 + n16] = f2bf(e1);
            Plds[(pr + 2) * 72 + js * 16 + n16] = f2bf(e2);
            Plds[(pr + 3) * 72 + js * 16 + n16] = f2bf(e3);
        }
        __syncthreads();                     // Plds visible to all waves

        // prefetch K[t+1] into the alternate buffer — rides under PV
        if (t + 1 < NT) {
#pragma unroll
            for (int it = 0; it < 8; ++it) {
                int row = w * 8 + it;
                __builtin_amdgcn_global_load_lds(
                    (const __attribute__((address_space(1))) unsigned int*)
                        (kTb + (size_t)(j0 + 64 + row) * CC_ + lane * 8),
                    (__attribute__((address_space(3))) unsigned int*)
                        (&Klds[(t + 1) & 1][row * 520]),
                    16, 0, 0);
            }
        }

        // PV: all 128 queries x wave's 64-channel slice; V already in regs
#pragma unroll
        for (int mt = 0; mt < 8; ++mt) {
            const ushort_t* pr = &Plds[(mt * 16 + n16) * 72 + quad * 8];
            bf16x8 ap0 = *(const bf16x8*)(pr);
            bf16x8 ap1 = *(const bf16x8*)(pr + 32);
#pragma unroll
            for (int st = 0; st < 4; ++st) {
                acc[mt][st] = __builtin_amdgcn_mfma_f32_16x16x32_bf16(ap0, bv0[st], acc[mt][st], 0, 0, 0);
                acc[mt][st] = __builtin_amdgcn_mfma_f32_16x16x32_bf16(ap1, bv1[st], acc[mt][st], 0, 0, 0);
            }
        }
    }

    if (n16 == 0) {
        float* lp = lpart + ((size_t)b * NCH + chunk) * NN + i0 + w * 16 + quad * 4;
        lp[0] = lsum[0]; lp[1] = lsum[1]; lp[2] = lsum[2]; lp[3] = lsum[3];
    }
    ushort_t* opb = opart + ((size_t)b * NCH + chunk) * CC_ * NN;
#pragma unroll
    for (int mt = 0; mt < 8; ++mt)
#pragma unroll
        for (int st = 0; st < 4; ++st) {
            int c = cb + st * 16 + n16;
            int n = i0 + mt * 16 + quad * 4;
            ushort4 u;
            u.x = f2bf(acc[mt][st][0]); u.y = f2bf(acc[mt][st][1]);
            u.z = f2bf(acc[mt][st][2]); u.w = f2bf(acc[mt][st][3]);
            *(ushort4*)&opb[(size_t)c * NN + n] = u;
        }
}

// ------------- combine partials -> attnT bf16 [B][N][C] — R3-proven -------------
__global__ __launch_bounds__(256) void combine(const ushort_t* __restrict__ opart,
                                               const float* __restrict__ lpart,
                                               ushort_t* __restrict__ attnT) {
    const int b  = blockIdx.z;
    const int c0 = blockIdx.y * 64;
    const int n0 = blockIdx.x * 64;
    __shared__ float S[64][65];
    const int tid = threadIdx.x;
#pragma unroll
    for (int it = 0; it < 4; ++it) {
        int c  = it * 16 + (tid >> 4);
        int n4 = (tid & 15) * 4;
        float s0 = 0.f, s1 = 0.f, s2 = 0.f, s3 = 0.f;
#pragma unroll
        for (int k = 0; k < NCH; ++k) {
            ushort4 u = *(const ushort4*)&opart[(((size_t)b * NCH + k) * CC_ + c0 + c) * NN + n0 + n4];
            s0 += bf2f(u.x); s1 += bf2f(u.y); s2 += bf2f(u.z); s3 += bf2f(u.w);
        }
        S[c][n4 + 0] = s0; S[c][n4 + 1] = s1; S[c][n4 + 2] = s2; S[c][n4 + 3] = s3;
    }
    __syncthreads();
#pragma unroll
    for (int it = 0; it < 4; ++it) {
        int n  = it * 16 + (tid >> 4);
        int c4 = (tid & 15) * 4;
        float l = 0.f;
#pragma unroll
        for (int k = 0; k < NCH; ++k) l += lpart[((size_t)b * NCH + k) * NN + n0 + n];
        float linv = 1.0f / l;
        ushort4 u;
        u.x = f2bf(S[c4 + 0][n] * linv); u.y = f2bf(S[c4 + 1][n] * linv);
        u.z = f2bf(S[c4 + 2][n] * linv); u.w = f2bf(S[c4 + 3][n] * linv);
        *(ushort4*)&attnT[((size_t)b * NN + n0 + n) * CC_ + c0 + c4] = u;
    }
}

// ---------------- proj conv (MFMA): tile 128m x 64o, grid (64, 8) — R6-proven ----------------
__global__ __launch_bounds__(256) void conv_proj(const ushort_t* __restrict__ attnT,
                                                 const ushort_t* __restrict__ wpb,
                                                 const float* __restrict__ bp,
                                                 const float* __restrict__ x,
                                                 float* __restrict__ out) {
    constexpr int ASTR = 40;
    __shared__ __align__(16) char smem[33792];   // max((128+64)*40*2, 64*132*4)
    ushort_t* At = (ushort_t*)smem;              // [128 m][40]
    ushort_t* Bt = At + 128 * ASTR;              // [64 o][40]

    const int m0 = blockIdx.x * 128;
    const int o0 = blockIdx.y * 64;
    const int tid = threadIdx.x;
    const int w = tid >> 6, lane = tid & 63, quad = lane >> 4, n16 = lane & 15;
    const int wm = w & 1, wn = w >> 1;
    const int r2 = tid >> 1, half = tid & 1;

    floatx4 acc[4][2];
#pragma unroll
    for (int i = 0; i < 4; ++i)
#pragma unroll
        for (int j = 0; j < 2; ++j) acc[i][j] = (floatx4){0.f, 0.f, 0.f, 0.f};

    for (int k0 = 0; k0 < CC_; k0 += 32) {
        const ushort_t* asrc = &attnT[(size_t)(m0 + r2) * CC_ + k0 + half * 16];
        bf16x8 a0 = *(const bf16x8*)(asrc);
        bf16x8 a1 = *(const bf16x8*)(asrc + 8);
        bf16x8 w0, w1;
        if (tid < 128) {
            const ushort_t* wsrc = &wpb[(size_t)(o0 + r2) * CC_ + k0 + half * 16];
            w0 = *(const bf16x8*)(wsrc);
            w1 = *(const bf16x8*)(wsrc + 8);
        }
        __syncthreads();
        *(bf16x8*)&At[r2 * ASTR + half * 16]     = a0;
        *(bf16x8*)&At[r2 * ASTR + half * 16 + 8] = a1;
        if (tid < 128) {
            *(bf16x8*)&Bt[r2 * ASTR + half * 16]     = w0;
            *(bf16x8*)&Bt[r2 * ASTR + half * 16 + 8] = w1;
        }
        __syncthreads();
        bf16x8 af[4], bf_[2];
#pragma unroll
        for (int mt = 0; mt < 4; ++mt)
            af[mt] = *(const bf16x8*)&At[(wm * 64 + mt * 16 + n16) * ASTR + quad * 8];
#pragma unroll
        for (int nt = 0; nt < 2; ++nt)
            bf_[nt] = *(const bf16x8*)&Bt[(wn * 32 + nt * 16 + n16) * ASTR + quad * 8];
#pragma unroll
        for (int mt = 0; mt < 4; ++mt)
#pragma unroll
            for (int nt = 0; nt < 2; ++nt)
                acc[mt][nt] = __builtin_amdgcn_mfma_f32_16x16x32_bf16(af[mt], bf_[nt], acc[mt][nt], 0, 0, 0);
    }

    float bsv[2];
#pragma unroll
    for (int nt = 0; nt < 2; ++nt) bsv[nt] = bp[o0 + wn * 32 + nt * 16 + n16];

    __syncthreads();
    float* Tf = (float*)smem;                    // [64 o][132]
#pragma unroll
    for (int mt = 0; mt < 4; ++mt)
#pragma unroll
        for (int nt = 0; nt < 2; ++nt) {
            int ol = wn * 32 + nt * 16 + n16;
#pragma unroll
            for (int r = 0; r < 4; ++r) {
                int nl = wm * 64 + mt * 16 + quad * 4 + r;
                Tf[ol * 132 + nl] = acc[mt][nt][r] + bsv[nt];
            }
        }
    __syncthreads();
    const int bb = m0 >> 12;
    const int n0 = m0 & (NN - 1);
    const int ro = tid >> 2;                     // 0..63
    const int cc = (tid & 3) * 32;
    const size_t obase = ((size_t)bb * CC_ + o0 + ro) * NN + n0 + cc;
#pragma unroll
    for (int i = 0; i < 8; ++i) {
        float4 v  = *(const float4*)&Tf[ro * 132 + cc + i * 4];
        float4 x4 = *(const float4*)&x[obase + i * 4];
        v.x += x4.x; v.y += x4.y; v.z += x4.z; v.w += x4.w;
        *(float4*)&out[obase + i * 4] = v;
    }
}

extern "C" void kernel_launch(void* const* d_in, const int* in_sizes, int n_in,
                              void* d_out, int out_size, void* d_ws, size_t ws_size,
                              hipStream_t stream) {
    const float* x        = (const float*)d_in[0];
    const float* gn_scale = (const float*)d_in[1];
    const float* gn_bias  = (const float*)d_in[2];
    const float* wq = (const float*)d_in[3];
    const float* bq = (const float*)d_in[4];
    const float* wk = (const float*)d_in[5];
    const float* bk = (const float*)d_in[6];
    const float* wv = (const float*)d_in[7];
    const float* bv = (const float*)d_in[8];
    const float* wp = (const float*)d_in[9];
    const float* bp = (const float*)d_in[10];
    float* outp = (float*)d_out;

    const size_t TENS = (size_t)BB * CC_ * NN;       // 4,194,304 elements
    ushort_t* hT    = (ushort_t*)d_ws;               // bf16 [B][N][C]
    ushort_t* qT    = hT    + TENS;
    ushort_t* kT    = qT    + TENS;
    ushort_t* vB    = kT    + TENS;                  // bf16 [B][C][N]
    ushort_t* attnT = vB    + TENS;                  // bf16 [B][N][C]
    ushort_t* opart = attnT + TENS;                  // bf16 [B][NCH][C][N]
    ushort_t* wqkv  = opart + (size_t)NCH * TENS;    // bf16 [1536][512]
    ushort_t* wpb   = wqkv  + (size_t)1536 * 512;    // bf16 [512][512]
    float*    lpart = (float*)(wpb + (size_t)512 * 512);  // [B][NCH][NN]
    float*    mv    = lpart + (size_t)BB * NCH * NN;      // 128 floats

    wprep<<<1024, 256, 0, stream>>>(wq, wk, wv, wp, wqkv, wpb);
    gn_stats<<<BB * GG, 256, 0, stream>>>(x, mv);
    gn_apply_t<<<dim3(NN / 64, CC_ / 64, BB), 256, 0, stream>>>(x, gn_scale, gn_bias, mv, hT);

    conv_qkv<<<dim3(BB * NN / 128, 1536 / 128), 256, 0, stream>>>(
        hT, wqkv, bq, bk, bv, qT, kT, vB);

    flash_attn4<<<dim3(NN / 128, NCH, BB), 512, 0, stream>>>(qT, kT, vB, opart, lpart);
    combine<<<dim3(NN / 64, CC_ / 64, BB), 256, 0, stream>>>(opart, lpart, attnT);

    conv_proj<<<dim3(BB * NN / 128, CC_ / 64), 256, 0, stream>>>(attnT, wpb, bp, x, outp);
}

// Round 8
// 288.643 us; speedup vs baseline: 1.5740x; 1.0050x over previous
//
#include <hip/hip_runtime.h>
#include <math.h>

#define BB 2
#define CC_ 512
#define GG 32
#define CG 16
#define NN 4096
#define NCH 4
#define EPSF 1e-6f
#define SCALEF 0.04419417382415922f   // 1/sqrt(512)

typedef unsigned short ushort_t;
typedef __bf16 bf16x8 __attribute__((ext_vector_type(8)));
typedef ushort_t ushortx8 __attribute__((ext_vector_type(8)));
typedef float floatx4 __attribute__((ext_vector_type(4)));

__device__ __forceinline__ ushort_t f2bf(float f) {
    union { float f; unsigned u; } x; x.f = f;
    unsigned r = (x.u + 0x7FFFu + ((x.u >> 16) & 1u)) >> 16;   // RNE
    return (ushort_t)r;
}
__device__ __forceinline__ float bf2f(ushort_t v) {
    union { unsigned u; float f; } x; x.u = ((unsigned)v) << 16; return x.f;
}

// ---------------- weight prep: fp32 -> bf16, qkv packed [1536][512] ----------------
__global__ __launch_bounds__(256) void wprep(const float* __restrict__ wq,
                                             const float* __restrict__ wk,
                                             const float* __restrict__ wv,
                                             const float* __restrict__ wp,
                                             ushort_t* __restrict__ wqkv,
                                             ushort_t* __restrict__ wpb) {
    int idx4 = blockIdx.x * 256 + threadIdx.x;     // 4*65536 float4 total
    int m = idx4 >> 16;
    int r = idx4 & 65535;
    const float* src = (m == 0) ? wq : (m == 1) ? wk : (m == 2) ? wv : wp;
    float4 v = ((const float4*)src)[r];
    ushort4 u;
    u.x = f2bf(v.x); u.y = f2bf(v.y); u.z = f2bf(v.z); u.w = f2bf(v.w);
    if (m < 3) ((ushort4*)wqkv)[(size_t)m * 65536 + r] = u;
    else       ((ushort4*)wpb)[r] = u;
}

// ---------------- GroupNorm stats: one block per (b,g) ----------------
__global__ __launch_bounds__(256) void gn_stats(const float* __restrict__ x,
                                                float* __restrict__ mv) {
    int bg = blockIdx.x;
    const float4* xp = (const float4*)(x + (size_t)bg * (CG * NN));
    float s = 0.f, ss = 0.f;
    for (int idx = threadIdx.x; idx < CG * NN / 4; idx += 256) {
        float4 v = xp[idx];
        s  += (v.x + v.y) + (v.z + v.w);
        ss += v.x * v.x + v.y * v.y + v.z * v.z + v.w * v.w;
    }
    __shared__ float sm[8];
    for (int off = 32; off > 0; off >>= 1) {
        s  += __shfl_down(s, off, 64);
        ss += __shfl_down(ss, off, 64);
    }
    int lane = threadIdx.x & 63, wv = threadIdx.x >> 6;
    if (lane == 0) { sm[wv] = s; sm[4 + wv] = ss; }
    __syncthreads();
    if (threadIdx.x == 0) {
        s  = sm[0] + sm[1] + sm[2] + sm[3];
        ss = sm[4] + sm[5] + sm[6] + sm[7];
        const float inv = 1.0f / (float)(CG * NN);
        float mean = s * inv;
        float var  = ss * inv - mean * mean;
        mv[bg]      = mean;
        mv[64 + bg] = rsqrtf(var + EPSF);
    }
}

// ------------- GN apply + transpose: hT bf16 [B][N][C] -------------
__global__ __launch_bounds__(256) void gn_apply_t(const float* __restrict__ x,
                                                  const float* __restrict__ gamma,
                                                  const float* __restrict__ beta,
                                                  const float* __restrict__ mv,
                                                  ushort_t* __restrict__ hT) {
    const int b  = blockIdx.z;
    const int c0 = blockIdx.y * 64;
    const int n0 = blockIdx.x * 64;
    __shared__ float T[64][65];
    const int tid = threadIdx.x;
#pragma unroll
    for (int it = 0; it < 4; ++it) {
        int c  = it * 16 + (tid >> 4);
        int n4 = (tid & 15) * 4;
        int bg = b * 32 + ((c0 + c) >> 4);
        float a  = mv[64 + bg] * gamma[c0 + c];
        float b2 = beta[c0 + c] - mv[bg] * a;
        float4 v = *(const float4*)&x[((size_t)b * CC_ + c0 + c) * NN + n0 + n4];
        T[c][n4 + 0] = v.x * a + b2;
        T[c][n4 + 1] = v.y * a + b2;
        T[c][n4 + 2] = v.z * a + b2;
        T[c][n4 + 3] = v.w * a + b2;
    }
    __syncthreads();
#pragma unroll
    for (int it = 0; it < 4; ++it) {
        int n  = it * 16 + (tid >> 4);
        int c4 = (tid & 15) * 4;
        ushort4 u;
        u.x = f2bf(T[c4 + 0][n]); u.y = f2bf(T[c4 + 1][n]);
        u.z = f2bf(T[c4 + 2][n]); u.w = f2bf(T[c4 + 3][n]);
        *(ushort4*)&hT[((size_t)b * NN + n0 + n) * CC_ + c0 + c4] = u;
    }
}

// ---------------- fused QKV conv (MFMA): grid (64, 12) — R6-proven ----------------
__global__ __launch_bounds__(256) void conv_qkv(const ushort_t* __restrict__ hT,
                                                const ushort_t* __restrict__ wqkv,
                                                const float* __restrict__ bq,
                                                const float* __restrict__ bk,
                                                const float* __restrict__ bv,
                                                ushort_t* __restrict__ qT,
                                                ushort_t* __restrict__ kT,
                                                ushort_t* __restrict__ vB) {
    constexpr int ASTR = 40;
    __shared__ __align__(16) char smem[34816];   // max(2*128*40*2, 128*136*2)
    ushort_t* At = (ushort_t*)smem;
    ushort_t* Bt = At + 128 * ASTR;

    const int m0  = blockIdx.x * 128;            // global row (b*N+n)
    const int o0g = blockIdx.y * 128;            // 0..1535
    const int matid = o0g >> 9;
    const int o0 = o0g & 511;
    const int tid = threadIdx.x;
    const int w = tid >> 6, lane = tid & 63, quad = lane >> 4, n16 = lane & 15;
    const int wm = w & 1, wn = w >> 1;
    const int r2 = tid >> 1, half = tid & 1;

    floatx4 acc[4][4];
#pragma unroll
    for (int i = 0; i < 4; ++i)
#pragma unroll
        for (int j = 0; j < 4; ++j) acc[i][j] = (floatx4){0.f, 0.f, 0.f, 0.f};

    for (int k0 = 0; k0 < CC_; k0 += 32) {
        const ushort_t* asrc = &hT[(size_t)(m0 + r2) * CC_ + k0 + half * 16];
        bf16x8 a0 = *(const bf16x8*)(asrc);
        bf16x8 a1 = *(const bf16x8*)(asrc + 8);
        const ushort_t* wsrc = &wqkv[(size_t)(o0g + r2) * CC_ + k0 + half * 16];
        bf16x8 w0 = *(const bf16x8*)(wsrc);
        bf16x8 w1 = *(const bf16x8*)(wsrc + 8);
        __syncthreads();
        *(bf16x8*)&At[r2 * ASTR + half * 16]     = a0;
        *(bf16x8*)&At[r2 * ASTR + half * 16 + 8] = a1;
        *(bf16x8*)&Bt[r2 * ASTR + half * 16]     = w0;
        *(bf16x8*)&Bt[r2 * ASTR + half * 16 + 8] = w1;
        __syncthreads();
        bf16x8 af[4], bf_[4];
#pragma unroll
        for (int mt = 0; mt < 4; ++mt)
            af[mt] = *(const bf16x8*)&At[(wm * 64 + mt * 16 + n16) * ASTR + quad * 8];
#pragma unroll
        for (int nt = 0; nt < 4; ++nt)
            bf_[nt] = *(const bf16x8*)&Bt[(wn * 64 + nt * 16 + n16) * ASTR + quad * 8];
#pragma unroll
        for (int mt = 0; mt < 4; ++mt)
#pragma unroll
            for (int nt = 0; nt < 4; ++nt)
                acc[mt][nt] = __builtin_amdgcn_mfma_f32_16x16x32_bf16(af[mt], bf_[nt], acc[mt][nt], 0, 0, 0);
    }

    const float* bias = (matid == 0) ? bq : (matid == 1) ? bk : bv;
    float bsv[4];
#pragma unroll
    for (int nt = 0; nt < 4; ++nt) bsv[nt] = bias[o0 + wn * 64 + nt * 16 + n16];

    if (matid < 2) {
        float scale = (matid == 0) ? SCALEF : 1.0f;
        ushort_t* dst = (matid == 0) ? qT : kT;
#pragma unroll
        for (int mt = 0; mt < 4; ++mt)
#pragma unroll
            for (int nt = 0; nt < 4; ++nt) {
                int o = o0 + wn * 64 + nt * 16 + n16;
#pragma unroll
                for (int r = 0; r < 4; ++r) {
                    int m = m0 + wm * 64 + mt * 16 + quad * 4 + r;
                    dst[(size_t)m * CC_ + o] = f2bf((acc[mt][nt][r] + bsv[nt]) * scale);
                }
            }
    } else {
        __syncthreads();
        ushort_t* T = (ushort_t*)smem;           // [128 o][136]
#pragma unroll
        for (int mt = 0; mt < 4; ++mt)
#pragma unroll
            for (int nt = 0; nt < 4; ++nt) {
                int ol = wn * 64 + nt * 16 + n16;
#pragma unroll
                for (int r = 0; r < 4; ++r) {
                    int nl = wm * 64 + mt * 16 + quad * 4 + r;
                    T[ol * 136 + nl] = f2bf(acc[mt][nt][r] + bsv[nt]);
                }
            }
        __syncthreads();
        const int bb = m0 >> 12;
        const int n0 = m0 & (NN - 1);
#pragma unroll
        for (int i = 0; i < 8; ++i) {
            ushortx8 v = *(const ushortx8*)&T[r2 * 136 + half * 64 + i * 8];
            *(ushortx8*)&vB[((size_t)bb * CC_ + o0 + r2) * NN + n0 + half * 64 + i * 8] = v;
        }
    }
}

// ---------------- MFMA flash attention v5: R7 pipeline + hoisted row-sum butterfly ----
// The per-tile 4-step __shfl_xor butterfly (ds_bpermute -> LDS pipe) is replaced by
// per-lane partial sums; ONE butterfly after the K loop. Row-sum is commutative, so
// the result is identical. Removes ~16k LDS-pipe instrs per CU from the hot loop.
__global__ __launch_bounds__(512, 2) void flash_attn5(
        const ushort_t* __restrict__ qT, const ushort_t* __restrict__ kT,
        const ushort_t* __restrict__ vB,
        ushort_t* __restrict__ opart, float* __restrict__ lpart) {
    const int b     = blockIdx.z;
    const int chunk = blockIdx.y;
    const int i0    = blockIdx.x * 128;
    const ushort_t* qTb = qT + (size_t)b * NN * CC_;
    const ushort_t* kTb = kT + (size_t)b * NN * CC_;
    const ushort_t* vBb = vB + (size_t)b * CC_ * NN;

    __shared__ ushort_t Klds[2][64 * 520];   // 2 x 66.6 KB
    __shared__ ushort_t Plds[128 * 72];      // 18.4 KB

    const int tid  = threadIdx.x;
    const int w    = tid >> 6;
    const int lane = tid & 63;
    const int quad = lane >> 4;
    const int n16  = lane & 15;
    const int cb   = w * 64;

    bf16x8 aq[16];
    {
        const ushort_t* qrow = qTb + (size_t)(i0 + w * 16 + n16) * CC_ + quad * 8;
#pragma unroll
        for (int ks = 0; ks < 16; ++ks) aq[ks] = *(const bf16x8*)(qrow + ks * 32);
    }

    floatx4 acc[8][4];
#pragma unroll
    for (int mt = 0; mt < 8; ++mt)
#pragma unroll
        for (int st = 0; st < 4; ++st) acc[mt][st] = (floatx4){0.f, 0.f, 0.f, 0.f};
    float lsum[4] = {0.f, 0.f, 0.f, 0.f};   // per-lane partials; butterfly once at end

    const int jbase = chunk * (NN / NCH);
    constexpr int NT = (NN / NCH) / 64;      // 16 tiles

    // prefetch tile 0 into buffer 0
#pragma unroll
    for (int it = 0; it < 8; ++it) {
        int row = w * 8 + it;
        __builtin_amdgcn_global_load_lds(
            (const __attribute__((address_space(1))) unsigned int*)
                (kTb + (size_t)(jbase + row) * CC_ + lane * 8),
            (__attribute__((address_space(3))) unsigned int*)(&Klds[0][row * 520]),
            16, 0, 0);
    }

    for (int t = 0; t < NT; ++t) {
        const int j0 = jbase + t * 64;
        const ushort_t* Kbuf = Klds[t & 1];
        __syncthreads();                     // K[t] arrived; Plds free from t-1

        // V[t] loads — issue early, consumed after mid barrier
        bf16x8 bv0[4], bv1[4];
#pragma unroll
        for (int st = 0; st < 4; ++st) {
            const ushort_t* vp = vBb + (size_t)(cb + st * 16 + n16) * NN + j0 + quad * 8;
            bv0[st] = *(const bf16x8*)(vp);
            bv1[st] = *(const bf16x8*)(vp + 32);
        }

        // QK^T: wave's 16 queries x 64 keys (4 j-strips), exp, P -> LDS
#pragma unroll
        for (int js = 0; js < 4; ++js) {
            floatx4 s = (floatx4){0.f, 0.f, 0.f, 0.f};
            const ushort_t* kb = &Kbuf[(js * 16 + n16) * 520 + quad * 8];
#pragma unroll
            for (int ks = 0; ks < 16; ++ks) {
                bf16x8 bk = *(const bf16x8*)(kb + ks * 32);
                s = __builtin_amdgcn_mfma_f32_16x16x32_bf16(aq[ks], bk, s, 0, 0, 0);
            }
            float e0 = __expf(s[0]), e1 = __expf(s[1]);
            float e2 = __expf(s[2]), e3 = __expf(s[3]);
            lsum[0] += e0; lsum[1] += e1; lsum[2] += e2; lsum[3] += e3;
            const int pr = w * 16 + quad * 4;
            Plds[(pr + 0) * 72 + js * 16 + n16] = f2bf(e0);
            Plds[(pr + 1) * 72 + js * 16 + n16] = f2bf(e1);
            Plds[(pr + 2) * 72 + js * 16 + n16] = f2bf(e2);
            Plds[(pr + 3) * 72 + js * 16 + n16] = f2bf(e3);
        }
        __syncthreads();                     // Plds visible to all waves

        // prefetch K[t+1] into the alternate buffer — rides under PV
        if (t + 1 < NT) {
#pragma unroll
            for (int it = 0; it < 8; ++it) {
                int row = w * 8 + it;
                __builtin_amdgcn_global_load_lds(
                    (const __attribute__((address_space(1))) unsigned int*)
                        (kTb + (size_t)(j0 + 64 + row) * CC_ + lane * 8),
                    (__attribute__((address_space(3))) unsigned int*)
                        (&Klds[(t + 1) & 1][row * 520]),
                    16, 0, 0);
            }
        }

        // PV: all 128 queries x wave's 64-channel slice; V already in regs
#pragma unroll
        for (int mt = 0; mt < 8; ++mt) {
            const ushort_t* pr = &Plds[(mt * 16 + n16) * 72 + quad * 8];
            bf16x8 ap0 = *(const bf16x8*)(pr);
            bf16x8 ap1 = *(const bf16x8*)(pr + 32);
#pragma unroll
            for (int st = 0; st < 4; ++st) {
                acc[mt][st] = __builtin_amdgcn_mfma_f32_16x16x32_bf16(ap0, bv0[st], acc[mt][st], 0, 0, 0);
                acc[mt][st] = __builtin_amdgcn_mfma_f32_16x16x32_bf16(ap1, bv1[st], acc[mt][st], 0, 0, 0);
            }
        }
    }

    // single butterfly: reduce per-lane partials across the 16 lanes of each quad-row
#pragma unroll
    for (int r = 0; r < 4; ++r) {
        float p = lsum[r];
        p += __shfl_xor(p, 1);
        p += __shfl_xor(p, 2);
        p += __shfl_xor(p, 4);
        p += __shfl_xor(p, 8);
        lsum[r] = p;
    }

    if (n16 == 0) {
        float* lp = lpart + ((size_t)b * NCH + chunk) * NN + i0 + w * 16 + quad * 4;
        lp[0] = lsum[0]; lp[1] = lsum[1]; lp[2] = lsum[2]; lp[3] = lsum[3];
    }
    ushort_t* opb = opart + ((size_t)b * NCH + chunk) * CC_ * NN;
#pragma unroll
    for (int mt = 0; mt < 8; ++mt)
#pragma unroll
        for (int st = 0; st < 4; ++st) {
            int c = cb + st * 16 + n16;
            int n = i0 + mt * 16 + quad * 4;
            ushort4 u;
            u.x = f2bf(acc[mt][st][0]); u.y = f2bf(acc[mt][st][1]);
            u.z = f2bf(acc[mt][st][2]); u.w = f2bf(acc[mt][st][3]);
            *(ushort4*)&opb[(size_t)c * NN + n] = u;
        }
}

// ------------- combine partials -> attnT bf16 [B][N][C] — R3-proven -------------
__global__ __launch_bounds__(256) void combine(const ushort_t* __restrict__ opart,
                                               const float* __restrict__ lpart,
                                               ushort_t* __restrict__ attnT) {
    const int b  = blockIdx.z;
    const int c0 = blockIdx.y * 64;
    const int n0 = blockIdx.x * 64;
    __shared__ float S[64][65];
    const int tid = threadIdx.x;
#pragma unroll
    for (int it = 0; it < 4; ++it) {
        int c  = it * 16 + (tid >> 4);
        int n4 = (tid & 15) * 4;
        float s0 = 0.f, s1 = 0.f, s2 = 0.f, s3 = 0.f;
#pragma unroll
        for (int k = 0; k < NCH; ++k) {
            ushort4 u = *(const ushort4*)&opart[(((size_t)b * NCH + k) * CC_ + c0 + c) * NN + n0 + n4];
            s0 += bf2f(u.x); s1 += bf2f(u.y); s2 += bf2f(u.z); s3 += bf2f(u.w);
        }
        S[c][n4 + 0] = s0; S[c][n4 + 1] = s1; S[c][n4 + 2] = s2; S[c][n4 + 3] = s3;
    }
    __syncthreads();
#pragma unroll
    for (int it = 0; it < 4; ++it) {
        int n  = it * 16 + (tid >> 4);
        int c4 = (tid & 15) * 4;
        float l = 0.f;
#pragma unroll
        for (int k = 0; k < NCH; ++k) l += lpart[((size_t)b * NCH + k) * NN + n0 + n];
        float linv = 1.0f / l;
        ushort4 u;
        u.x = f2bf(S[c4 + 0][n] * linv); u.y = f2bf(S[c4 + 1][n] * linv);
        u.z = f2bf(S[c4 + 2][n] * linv); u.w = f2bf(S[c4 + 3][n] * linv);
        *(ushort4*)&attnT[((size_t)b * NN + n0 + n) * CC_ + c0 + c4] = u;
    }
}

// ---------------- proj conv (MFMA): tile 128m x 64o, grid (64, 8) — R6-proven ----------------
__global__ __launch_bounds__(256) void conv_proj(const ushort_t* __restrict__ attnT,
                                                 const ushort_t* __restrict__ wpb,
                                                 const float* __restrict__ bp,
                                                 const float* __restrict__ x,
                                                 float* __restrict__ out) {
    constexpr int ASTR = 40;
    __shared__ __align__(16) char smem[33792];   // max((128+64)*40*2, 64*132*4)
    ushort_t* At = (ushort_t*)smem;              // [128 m][40]
    ushort_t* Bt = At + 128 * ASTR;              // [64 o][40]

    const int m0 = blockIdx.x * 128;
    const int o0 = blockIdx.y * 64;
    const int tid = threadIdx.x;
    const int w = tid >> 6, lane = tid & 63, quad = lane >> 4, n16 = lane & 15;
    const int wm = w & 1, wn = w >> 1;
    const int r2 = tid >> 1, half = tid & 1;

    floatx4 acc[4][2];
#pragma unroll
    for (int i = 0; i < 4; ++i)
#pragma unroll
        for (int j = 0; j < 2; ++j) acc[i][j] = (floatx4){0.f, 0.f, 0.f, 0.f};

    for (int k0 = 0; k0 < CC_; k0 += 32) {
        const ushort_t* asrc = &attnT[(size_t)(m0 + r2) * CC_ + k0 + half * 16];
        bf16x8 a0 = *(const bf16x8*)(asrc);
        bf16x8 a1 = *(const bf16x8*)(asrc + 8);
        bf16x8 w0, w1;
        if (tid < 128) {
            const ushort_t* wsrc = &wpb[(size_t)(o0 + r2) * CC_ + k0 + half * 16];
            w0 = *(const bf16x8*)(wsrc);
            w1 = *(const bf16x8*)(wsrc + 8);
        }
        __syncthreads();
        *(bf16x8*)&At[r2 * ASTR + half * 16]     = a0;
        *(bf16x8*)&At[r2 * ASTR + half * 16 + 8] = a1;
        if (tid < 128) {
            *(bf16x8*)&Bt[r2 * ASTR + half * 16]     = w0;
            *(bf16x8*)&Bt[r2 * ASTR + half * 16 + 8] = w1;
        }
        __syncthreads();
        bf16x8 af[4], bf_[2];
#pragma unroll
        for (int mt = 0; mt < 4; ++mt)
            af[mt] = *(const bf16x8*)&At[(wm * 64 + mt * 16 + n16) * ASTR + quad * 8];
#pragma unroll
        for (int nt = 0; nt < 2; ++nt)
            bf_[nt] = *(const bf16x8*)&Bt[(wn * 32 + nt * 16 + n16) * ASTR + quad * 8];
#pragma unroll
        for (int mt = 0; mt < 4; ++mt)
#pragma unroll
            for (int nt = 0; nt < 2; ++nt)
                acc[mt][nt] = __builtin_amdgcn_mfma_f32_16x16x32_bf16(af[mt], bf_[nt], acc[mt][nt], 0, 0, 0);
    }

    float bsv[2];
#pragma unroll
    for (int nt = 0; nt < 2; ++nt) bsv[nt] = bp[o0 + wn * 32 + nt * 16 + n16];

    __syncthreads();
    float* Tf = (float*)smem;                    // [64 o][132]
#pragma unroll
    for (int mt = 0; mt < 4; ++mt)
#pragma unroll
        for (int nt = 0; nt < 2; ++nt) {
            int ol = wn * 32 + nt * 16 + n16;
#pragma unroll
            for (int r = 0; r < 4; ++r) {
                int nl = wm * 64 + mt * 16 + quad * 4 + r;
                Tf[ol * 132 + nl] = acc[mt][nt][r] + bsv[nt];
            }
        }
    __syncthreads();
    const int bb = m0 >> 12;
    const int n0 = m0 & (NN - 1);
    const int ro = tid >> 2;                     // 0..63
    const int cc = (tid & 3) * 32;
    const size_t obase = ((size_t)bb * CC_ + o0 + ro) * NN + n0 + cc;
#pragma unroll
    for (int i = 0; i < 8; ++i) {
        float4 v  = *(const float4*)&Tf[ro * 132 + cc + i * 4];
        float4 x4 = *(const float4*)&x[obase + i * 4];
        v.x += x4.x; v.y += x4.y; v.z += x4.z; v.w += x4.w;
        *(float4*)&out[obase + i * 4] = v;
    }
}

extern "C" void kernel_launch(void* const* d_in, const int* in_sizes, int n_in,
                              void* d_out, int out_size, void* d_ws, size_t ws_size,
                              hipStream_t stream) {
    const float* x        = (const float*)d_in[0];
    const float* gn_scale = (const float*)d_in[1];
    const float* gn_bias  = (const float*)d_in[2];
    const float* wq = (const float*)d_in[3];
    const float* bq = (const float*)d_in[4];
    const float* wk = (const float*)d_in[5];
    const float* bk = (const float*)d_in[6];
    const float* wv = (const float*)d_in[7];
    const float* bv = (const float*)d_in[8];
    const float* wp = (const float*)d_in[9];
    const float* bp = (const float*)d_in[10];
    float* outp = (float*)d_out;

    const size_t TENS = (size_t)BB * CC_ * NN;       // 4,194,304 elements
    ushort_t* hT    = (ushort_t*)d_ws;               // bf16 [B][N][C]
    ushort_t* qT    = hT    + TENS;
    ushort_t* kT    = qT    + TENS;
    ushort_t* vB    = kT    + TENS;                  // bf16 [B][C][N]
    ushort_t* attnT = vB    + TENS;                  // bf16 [B][N][C]
    ushort_t* opart = attnT + TENS;                  // bf16 [B][NCH][C][N]
    ushort_t* wqkv  = opart + (size_t)NCH * TENS;    // bf16 [1536][512]
    ushort_t* wpb   = wqkv  + (size_t)1536 * 512;    // bf16 [512][512]
    float*    lpart = (float*)(wpb + (size_t)512 * 512);  // [B][NCH][NN]
    float*    mv    = lpart + (size_t)BB * NCH * NN;      // 128 floats

    wprep<<<1024, 256, 0, stream>>>(wq, wk, wv, wp, wqkv, wpb);
    gn_stats<<<BB * GG, 256, 0, stream>>>(x, mv);
    gn_apply_t<<<dim3(NN / 64, CC_ / 64, BB), 256, 0, stream>>>(x, gn_scale, gn_bias, mv, hT);

    conv_qkv<<<dim3(BB * NN / 128, 1536 / 128), 256, 0, stream>>>(
        hT, wqkv, bq, bk, bv, qT, kT, vB);

    flash_attn5<<<dim3(NN / 128, NCH, BB), 512, 0, stream>>>(qT, kT, vB, opart, lpart);
    combine<<<dim3(NN / 64, CC_ / 64, BB), 256, 0, stream>>>(opart, lpart, attnT);

    conv_proj<<<dim3(BB * NN / 128, CC_ / 64), 256, 0, stream>>>(attnT, wpb, bp, x, outp);
}

// Round 9
// 265.806 us; speedup vs baseline: 1.7093x; 1.0859x over previous
//
#include <hip/hip_runtime.h>
#include <math.h>

#define BB 2
#define CC_ 512
#define GG 32
#define CG 16
#define NN 4096
#define NCH 4
#define EPSF 1e-6f
#define SCALEF 0.04419417382415922f   // 1/sqrt(512)

typedef unsigned short ushort_t;
typedef __bf16 bf16x8 __attribute__((ext_vector_type(8)));
typedef ushort_t ushortx8 __attribute__((ext_vector_type(8)));
typedef float floatx4 __attribute__((ext_vector_type(4)));

__device__ __forceinline__ ushort_t f2bf(float f) {
    union { float f; unsigned u; } x; x.f = f;
    unsigned r = (x.u + 0x7FFFu + ((x.u >> 16) & 1u)) >> 16;   // RNE
    return (ushort_t)r;
}
__device__ __forceinline__ float bf2f(ushort_t v) {
    union { unsigned u; float f; } x; x.u = ((unsigned)v) << 16; return x.f;
}

// ---------------- weight prep: fp32 -> bf16, qkv packed [1536][512] ----------------
__global__ __launch_bounds__(256) void wprep(const float* __restrict__ wq,
                                             const float* __restrict__ wk,
                                             const float* __restrict__ wv,
                                             const float* __restrict__ wp,
                                             ushort_t* __restrict__ wqkv,
                                             ushort_t* __restrict__ wpb) {
    int idx4 = blockIdx.x * 256 + threadIdx.x;     // 4*65536 float4 total
    int m = idx4 >> 16;
    int r = idx4 & 65535;
    const float* src = (m == 0) ? wq : (m == 1) ? wk : (m == 2) ? wv : wp;
    float4 v = ((const float4*)src)[r];
    ushort4 u;
    u.x = f2bf(v.x); u.y = f2bf(v.y); u.z = f2bf(v.z); u.w = f2bf(v.w);
    if (m < 3) ((ushort4*)wqkv)[(size_t)m * 65536 + r] = u;
    else       ((ushort4*)wpb)[r] = u;
}

// ---------------- GroupNorm stats: one block per (b,g) ----------------
__global__ __launch_bounds__(256) void gn_stats(const float* __restrict__ x,
                                                float* __restrict__ mv) {
    int bg = blockIdx.x;
    const float4* xp = (const float4*)(x + (size_t)bg * (CG * NN));
    float s = 0.f, ss = 0.f;
    for (int idx = threadIdx.x; idx < CG * NN / 4; idx += 256) {
        float4 v = xp[idx];
        s  += (v.x + v.y) + (v.z + v.w);
        ss += v.x * v.x + v.y * v.y + v.z * v.z + v.w * v.w;
    }
    __shared__ float sm[8];
    for (int off = 32; off > 0; off >>= 1) {
        s  += __shfl_down(s, off, 64);
        ss += __shfl_down(ss, off, 64);
    }
    int lane = threadIdx.x & 63, wv = threadIdx.x >> 6;
    if (lane == 0) { sm[wv] = s; sm[4 + wv] = ss; }
    __syncthreads();
    if (threadIdx.x == 0) {
        s  = sm[0] + sm[1] + sm[2] + sm[3];
        ss = sm[4] + sm[5] + sm[6] + sm[7];
        const float inv = 1.0f / (float)(CG * NN);
        float mean = s * inv;
        float var  = ss * inv - mean * mean;
        mv[bg]      = mean;
        mv[64 + bg] = rsqrtf(var + EPSF);
    }
}

// ------------- GN apply + transpose: hT bf16 [B][N][C] -------------
__global__ __launch_bounds__(256) void gn_apply_t(const float* __restrict__ x,
                                                  const float* __restrict__ gamma,
                                                  const float* __restrict__ beta,
                                                  const float* __restrict__ mv,
                                                  ushort_t* __restrict__ hT) {
    const int b  = blockIdx.z;
    const int c0 = blockIdx.y * 64;
    const int n0 = blockIdx.x * 64;
    __shared__ float T[64][65];
    const int tid = threadIdx.x;
#pragma unroll
    for (int it = 0; it < 4; ++it) {
        int c  = it * 16 + (tid >> 4);
        int n4 = (tid & 15) * 4;
        int bg = b * 32 + ((c0 + c) >> 4);
        float a  = mv[64 + bg] * gamma[c0 + c];
        float b2 = beta[c0 + c] - mv[bg] * a;
        float4 v = *(const float4*)&x[((size_t)b * CC_ + c0 + c) * NN + n0 + n4];
        T[c][n4 + 0] = v.x * a + b2;
        T[c][n4 + 1] = v.y * a + b2;
        T[c][n4 + 2] = v.z * a + b2;
        T[c][n4 + 3] = v.w * a + b2;
    }
    __syncthreads();
#pragma unroll
    for (int it = 0; it < 4; ++it) {
        int n  = it * 16 + (tid >> 4);
        int c4 = (tid & 15) * 4;
        ushort4 u;
        u.x = f2bf(T[c4 + 0][n]); u.y = f2bf(T[c4 + 1][n]);
        u.z = f2bf(T[c4 + 2][n]); u.w = f2bf(T[c4 + 3][n]);
        *(ushort4*)&hT[((size_t)b * NN + n0 + n) * CC_ + c0 + c4] = u;
    }
}

// ---------------- fused QKV conv (MFMA), BK=64: grid (64, 12) ----------------
__global__ __launch_bounds__(256) void conv_qkv(const ushort_t* __restrict__ hT,
                                                const ushort_t* __restrict__ wqkv,
                                                const float* __restrict__ bq,
                                                const float* __restrict__ bk,
                                                const float* __restrict__ bv,
                                                ushort_t* __restrict__ qT,
                                                ushort_t* __restrict__ kT,
                                                ushort_t* __restrict__ vB) {
    constexpr int ASTR = 72;                     // 64 ch + 8 pad
    __shared__ __align__(16) char smem[36864];   // max(2*128*72*2, 128*136*2)
    ushort_t* At = (ushort_t*)smem;
    ushort_t* Bt = At + 128 * ASTR;

    const int m0  = blockIdx.x * 128;            // global row (b*N+n)
    const int o0g = blockIdx.y * 128;            // 0..1535
    const int matid = o0g >> 9;
    const int o0 = o0g & 511;
    const int tid = threadIdx.x;
    const int w = tid >> 6, lane = tid & 63, quad = lane >> 4, n16 = lane & 15;
    const int wm = w & 1, wn = w >> 1;
    const int r2 = tid >> 1, half = tid & 1;

    floatx4 acc[4][4];
#pragma unroll
    for (int i = 0; i < 4; ++i)
#pragma unroll
        for (int j = 0; j < 4; ++j) acc[i][j] = (floatx4){0.f, 0.f, 0.f, 0.f};

    for (int k0 = 0; k0 < CC_; k0 += 64) {
        const ushort_t* asrc = &hT[(size_t)(m0 + r2) * CC_ + k0 + half * 32];
        bf16x8 a0 = *(const bf16x8*)(asrc);
        bf16x8 a1 = *(const bf16x8*)(asrc + 8);
        bf16x8 a2 = *(const bf16x8*)(asrc + 16);
        bf16x8 a3 = *(const bf16x8*)(asrc + 24);
        const ushort_t* wsrc = &wqkv[(size_t)(o0g + r2) * CC_ + k0 + half * 32];
        bf16x8 w0 = *(const bf16x8*)(wsrc);
        bf16x8 w1 = *(const bf16x8*)(wsrc + 8);
        bf16x8 w2 = *(const bf16x8*)(wsrc + 16);
        bf16x8 w3 = *(const bf16x8*)(wsrc + 24);
        __syncthreads();
        {
            ushort_t* ad = &At[r2 * ASTR + half * 32];
            *(bf16x8*)(ad)      = a0; *(bf16x8*)(ad + 8)  = a1;
            *(bf16x8*)(ad + 16) = a2; *(bf16x8*)(ad + 24) = a3;
            ushort_t* bd = &Bt[r2 * ASTR + half * 32];
            *(bf16x8*)(bd)      = w0; *(bf16x8*)(bd + 8)  = w1;
            *(bf16x8*)(bd + 16) = w2; *(bf16x8*)(bd + 24) = w3;
        }
        __syncthreads();
#pragma unroll
        for (int ks2 = 0; ks2 < 2; ++ks2) {
            bf16x8 af[4], bf_[4];
#pragma unroll
            for (int mt = 0; mt < 4; ++mt)
                af[mt] = *(const bf16x8*)&At[(wm * 64 + mt * 16 + n16) * ASTR + ks2 * 32 + quad * 8];
#pragma unroll
            for (int nt = 0; nt < 4; ++nt)
                bf_[nt] = *(const bf16x8*)&Bt[(wn * 64 + nt * 16 + n16) * ASTR + ks2 * 32 + quad * 8];
#pragma unroll
            for (int mt = 0; mt < 4; ++mt)
#pragma unroll
                for (int nt = 0; nt < 4; ++nt)
                    acc[mt][nt] = __builtin_amdgcn_mfma_f32_16x16x32_bf16(af[mt], bf_[nt], acc[mt][nt], 0, 0, 0);
        }
    }

    const float* bias = (matid == 0) ? bq : (matid == 1) ? bk : bv;
    float bsv[4];
#pragma unroll
    for (int nt = 0; nt < 4; ++nt) bsv[nt] = bias[o0 + wn * 64 + nt * 16 + n16];

    if (matid < 2) {
        float scale = (matid == 0) ? SCALEF : 1.0f;
        ushort_t* dst = (matid == 0) ? qT : kT;
#pragma unroll
        for (int mt = 0; mt < 4; ++mt)
#pragma unroll
            for (int nt = 0; nt < 4; ++nt) {
                int o = o0 + wn * 64 + nt * 16 + n16;
#pragma unroll
                for (int r = 0; r < 4; ++r) {
                    int m = m0 + wm * 64 + mt * 16 + quad * 4 + r;
                    dst[(size_t)m * CC_ + o] = f2bf((acc[mt][nt][r] + bsv[nt]) * scale);
                }
            }
    } else {
        __syncthreads();
        ushort_t* T = (ushort_t*)smem;           // [128 o][136]
#pragma unroll
        for (int mt = 0; mt < 4; ++mt)
#pragma unroll
            for (int nt = 0; nt < 4; ++nt) {
                int ol = wn * 64 + nt * 16 + n16;
#pragma unroll
                for (int r = 0; r < 4; ++r) {
                    int nl = wm * 64 + mt * 16 + quad * 4 + r;
                    T[ol * 136 + nl] = f2bf(acc[mt][nt][r] + bsv[nt]);
                }
            }
        __syncthreads();
        const int bb = m0 >> 12;
        const int n0 = m0 & (NN - 1);
#pragma unroll
        for (int i = 0; i < 8; ++i) {
            ushortx8 v = *(const ushortx8*)&T[r2 * 136 + half * 64 + i * 8];
            *(ushortx8*)&vB[((size_t)bb * CC_ + o0 + r2) * NN + n0 + half * 64 + i * 8] = v;
        }
    }
}

// ---------------- MFMA flash attention v6: single-region pipelined tiles ----------------
// 32-key tiles; K and P double-buffered. Region t (between barriers) executes:
//   DMA K[t+1] -> Klds[(t+1)&1]   (drained at next barrier)
//   V[t-1] global loads -> regs   (hidden under QK)
//   QK(t): read Klds[t&1], write Plds[t&1]
//   PV(t-1): read Plds[(t-1)&1] + V regs   (MFMA-heavy, co-issues with QK LDS reads)
// Parity safety: P[t&1] last read in region t-1 (PV(t-2)); K[(t+1)&1] last read
// in region t-1 (QK(t-1)); both behind barrier B_t.
__global__ __launch_bounds__(512, 2) void flash_attn6(
        const ushort_t* __restrict__ qT, const ushort_t* __restrict__ kT,
        const ushort_t* __restrict__ vB,
        ushort_t* __restrict__ opart, float* __restrict__ lpart) {
    const int b     = blockIdx.z;
    const int chunk = blockIdx.y;
    const int i0    = blockIdx.x * 128;
    const ushort_t* qTb = qT + (size_t)b * NN * CC_;
    const ushort_t* kTb = kT + (size_t)b * NN * CC_;
    const ushort_t* vBb = vB + (size_t)b * CC_ * NN;

    __shared__ ushort_t Klds[2][32 * 520];   // 2 x 33.3 KB
    __shared__ ushort_t Plds[2][128 * 40];   // 2 x 10.25 KB  (stride 40 = 32 j + 8)

    const int tid  = threadIdx.x;
    const int w    = tid >> 6;
    const int lane = tid & 63;
    const int quad = lane >> 4;
    const int n16  = lane & 15;
    const int cb   = w * 64;

    bf16x8 aq[16];
    {
        const ushort_t* qrow = qTb + (size_t)(i0 + w * 16 + n16) * CC_ + quad * 8;
#pragma unroll
        for (int ks = 0; ks < 16; ++ks) aq[ks] = *(const bf16x8*)(qrow + ks * 32);
    }

    floatx4 acc[8][4];
#pragma unroll
    for (int mt = 0; mt < 8; ++mt)
#pragma unroll
        for (int st = 0; st < 4; ++st) acc[mt][st] = (floatx4){0.f, 0.f, 0.f, 0.f};
    float lsum[4] = {0.f, 0.f, 0.f, 0.f};

    const int jbase = chunk * (NN / NCH);
    constexpr int NT = (NN / NCH) / 32;      // 32 tiles

    // prefetch tile 0 into K buffer 0 (4 rows per wave)
#pragma unroll
    for (int it = 0; it < 4; ++it) {
        int row = w * 4 + it;
        __builtin_amdgcn_global_load_lds(
            (const __attribute__((address_space(1))) unsigned int*)
                (kTb + (size_t)(jbase + row) * CC_ + lane * 8),
            (__attribute__((address_space(3))) unsigned int*)(&Klds[0][row * 520]),
            16, 0, 0);
    }
    __syncthreads();                          // B0: K[0] ready

    for (int t = 0; t < NT; ++t) {
        const ushort_t* Kbuf = Klds[t & 1];
        ushort_t*       Pcur = Plds[t & 1];

        // DMA K[t+1] into alternate buffer
        if (t + 1 < NT) {
            const int jn = jbase + (t + 1) * 32;
#pragma unroll
            for (int it = 0; it < 4; ++it) {
                int row = w * 4 + it;
                __builtin_amdgcn_global_load_lds(
                    (const __attribute__((address_space(1))) unsigned int*)
                        (kTb + (size_t)(jn + row) * CC_ + lane * 8),
                    (__attribute__((address_space(3))) unsigned int*)
                        (&Klds[(t + 1) & 1][row * 520]),
                    16, 0, 0);
            }
        }

        // V[t-1] loads (consumed by PV below; latency hidden under QK)
        bf16x8 bv[4];
        if (t > 0) {
            const int jp = jbase + (t - 1) * 32;
#pragma unroll
            for (int st = 0; st < 4; ++st)
                bv[st] = *(const bf16x8*)(vBb + (size_t)(cb + st * 16 + n16) * NN + jp + quad * 8);
        }

        // QK(t): wave's 16 queries x 32 keys (2 j-strips)
#pragma unroll
        for (int js = 0; js < 2; ++js) {
            floatx4 s = (floatx4){0.f, 0.f, 0.f, 0.f};
            const ushort_t* kb = &Kbuf[(js * 16 + n16) * 520 + quad * 8];
#pragma unroll
            for (int ks = 0; ks < 16; ++ks) {
                bf16x8 bk = *(const bf16x8*)(kb + ks * 32);
                s = __builtin_amdgcn_mfma_f32_16x16x32_bf16(aq[ks], bk, s, 0, 0, 0);
            }
            float e0 = __expf(s[0]), e1 = __expf(s[1]);
            float e2 = __expf(s[2]), e3 = __expf(s[3]);
            lsum[0] += e0; lsum[1] += e1; lsum[2] += e2; lsum[3] += e3;
            const int pr = w * 16 + quad * 4;
            Pcur[(pr + 0) * 40 + js * 16 + n16] = f2bf(e0);
            Pcur[(pr + 1) * 40 + js * 16 + n16] = f2bf(e1);
            Pcur[(pr + 2) * 40 + js * 16 + n16] = f2bf(e2);
            Pcur[(pr + 3) * 40 + js * 16 + n16] = f2bf(e3);
        }

        // PV(t-1): all 128 queries x wave's 64-ch slice (K=32 in one MFMA)
        if (t > 0) {
            const ushort_t* Pprev = Plds[(t - 1) & 1];
#pragma unroll
            for (int mt = 0; mt < 8; ++mt) {
                bf16x8 ap = *(const bf16x8*)&Pprev[(mt * 16 + n16) * 40 + quad * 8];
#pragma unroll
                for (int st = 0; st < 4; ++st)
                    acc[mt][st] = __builtin_amdgcn_mfma_f32_16x16x32_bf16(ap, bv[st], acc[mt][st], 0, 0, 0);
            }
        }

        __syncthreads();                      // B_{t+1}: K[t+1] drained, P[t] visible
    }

    // epilogue: PV(NT-1)
    {
        const int jp = jbase + (NT - 1) * 32;
        bf16x8 bv[4];
#pragma unroll
        for (int st = 0; st < 4; ++st)
            bv[st] = *(const bf16x8*)(vBb + (size_t)(cb + st * 16 + n16) * NN + jp + quad * 8);
        const ushort_t* Pprev = Plds[(NT - 1) & 1];
#pragma unroll
        for (int mt = 0; mt < 8; ++mt) {
            bf16x8 ap = *(const bf16x8*)&Pprev[(mt * 16 + n16) * 40 + quad * 8];
#pragma unroll
            for (int st = 0; st < 4; ++st)
                acc[mt][st] = __builtin_amdgcn_mfma_f32_16x16x32_bf16(ap, bv[st], acc[mt][st], 0, 0, 0);
        }
    }

    // single butterfly for row sums
#pragma unroll
    for (int r = 0; r < 4; ++r) {
        float p = lsum[r];
        p += __shfl_xor(p, 1);
        p += __shfl_xor(p, 2);
        p += __shfl_xor(p, 4);
        p += __shfl_xor(p, 8);
        lsum[r] = p;
    }

    if (n16 == 0) {
        float* lp = lpart + ((size_t)b * NCH + chunk) * NN + i0 + w * 16 + quad * 4;
        lp[0] = lsum[0]; lp[1] = lsum[1]; lp[2] = lsum[2]; lp[3] = lsum[3];
    }
    ushort_t* opb = opart + ((size_t)b * NCH + chunk) * CC_ * NN;
#pragma unroll
    for (int mt = 0; mt < 8; ++mt)
#pragma unroll
        for (int st = 0; st < 4; ++st) {
            int c = cb + st * 16 + n16;
            int n = i0 + mt * 16 + quad * 4;
            ushort4 u;
            u.x = f2bf(acc[mt][st][0]); u.y = f2bf(acc[mt][st][1]);
            u.z = f2bf(acc[mt][st][2]); u.w = f2bf(acc[mt][st][3]);
            *(ushort4*)&opb[(size_t)c * NN + n] = u;
        }
}

// ------------- combine partials -> attnT bf16 [B][N][C] — R3-proven -------------
__global__ __launch_bounds__(256) void combine(const ushort_t* __restrict__ opart,
                                               const float* __restrict__ lpart,
                                               ushort_t* __restrict__ attnT) {
    const int b  = blockIdx.z;
    const int c0 = blockIdx.y * 64;
    const int n0 = blockIdx.x * 64;
    __shared__ float S[64][65];
    const int tid = threadIdx.x;
#pragma unroll
    for (int it = 0; it < 4; ++it) {
        int c  = it * 16 + (tid >> 4);
        int n4 = (tid & 15) * 4;
        float s0 = 0.f, s1 = 0.f, s2 = 0.f, s3 = 0.f;
#pragma unroll
        for (int k = 0; k < NCH; ++k) {
            ushort4 u = *(const ushort4*)&opart[(((size_t)b * NCH + k) * CC_ + c0 + c) * NN + n0 + n4];
            s0 += bf2f(u.x); s1 += bf2f(u.y); s2 += bf2f(u.z); s3 += bf2f(u.w);
        }
        S[c][n4 + 0] = s0; S[c][n4 + 1] = s1; S[c][n4 + 2] = s2; S[c][n4 + 3] = s3;
    }
    __syncthreads();
#pragma unroll
    for (int it = 0; it < 4; ++it) {
        int n  = it * 16 + (tid >> 4);
        int c4 = (tid & 15) * 4;
        float l = 0.f;
#pragma unroll
        for (int k = 0; k < NCH; ++k) l += lpart[((size_t)b * NCH + k) * NN + n0 + n];
        float linv = 1.0f / l;
        ushort4 u;
        u.x = f2bf(S[c4 + 0][n] * linv); u.y = f2bf(S[c4 + 1][n] * linv);
        u.z = f2bf(S[c4 + 2][n] * linv); u.w = f2bf(S[c4 + 3][n] * linv);
        *(ushort4*)&attnT[((size_t)b * NN + n0 + n) * CC_ + c0 + c4] = u;
    }
}

// ---------------- proj conv (MFMA), BK=64: tile 128m x 64o, grid (64, 8) ----------------
__global__ __launch_bounds__(256) void conv_proj(const ushort_t* __restrict__ attnT,
                                                 const ushort_t* __restrict__ wpb,
                                                 const float* __restrict__ bp,
                                                 const float* __restrict__ x,
                                                 float* __restrict__ out) {
    constexpr int ASTR = 72;
    __shared__ __align__(16) char smem[33792];   // max((128+64)*72*2=27648, 64*132*4=33792)
    ushort_t* At = (ushort_t*)smem;              // [128 m][72]
    ushort_t* Bt = At + 128 * ASTR;              // [64 o][72]

    const int m0 = blockIdx.x * 128;
    const int o0 = blockIdx.y * 64;
    const int tid = threadIdx.x;
    const int w = tid >> 6, lane = tid & 63, quad = lane >> 4, n16 = lane & 15;
    const int wm = w & 1, wn = w >> 1;
    const int r2 = tid >> 1, half = tid & 1;

    floatx4 acc[4][2];
#pragma unroll
    for (int i = 0; i < 4; ++i)
#pragma unroll
        for (int j = 0; j < 2; ++j) acc[i][j] = (floatx4){0.f, 0.f, 0.f, 0.f};

    for (int k0 = 0; k0 < CC_; k0 += 64) {
        const ushort_t* asrc = &attnT[(size_t)(m0 + r2) * CC_ + k0 + half * 32];
        bf16x8 a0 = *(const bf16x8*)(asrc);
        bf16x8 a1 = *(const bf16x8*)(asrc + 8);
        bf16x8 a2 = *(const bf16x8*)(asrc + 16);
        bf16x8 a3 = *(const bf16x8*)(asrc + 24);
        bf16x8 w0, w1, w2, w3;
        if (tid < 128) {
            const ushort_t* wsrc = &wpb[(size_t)(o0 + r2) * CC_ + k0 + half * 32];
            w0 = *(const bf16x8*)(wsrc);
            w1 = *(const bf16x8*)(wsrc + 8);
            w2 = *(const bf16x8*)(wsrc + 16);
            w3 = *(const bf16x8*)(wsrc + 24);
        }
        __syncthreads();
        {
            ushort_t* ad = &At[r2 * ASTR + half * 32];
            *(bf16x8*)(ad)      = a0; *(bf16x8*)(ad + 8)  = a1;
            *(bf16x8*)(ad + 16) = a2; *(bf16x8*)(ad + 24) = a3;
            if (tid < 128) {
                ushort_t* bd = &Bt[r2 * ASTR + half * 32];
                *(bf16x8*)(bd)      = w0; *(bf16x8*)(bd + 8)  = w1;
                *(bf16x8*)(bd + 16) = w2; *(bf16x8*)(bd + 24) = w3;
            }
        }
        __syncthreads();
#pragma unroll
        for (int ks2 = 0; ks2 < 2; ++ks2) {
            bf16x8 af[4], bf_[2];
#pragma unroll
            for (int mt = 0; mt < 4; ++mt)
                af[mt] = *(const bf16x8*)&At[(wm * 64 + mt * 16 + n16) * ASTR + ks2 * 32 + quad * 8];
#pragma unroll
            for (int nt = 0; nt < 2; ++nt)
                bf_[nt] = *(const bf16x8*)&Bt[(wn * 32 + nt * 16 + n16) * ASTR + ks2 * 32 + quad * 8];
#pragma unroll
            for (int mt = 0; mt < 4; ++mt)
#pragma unroll
                for (int nt = 0; nt < 2; ++nt)
                    acc[mt][nt] = __builtin_amdgcn_mfma_f32_16x16x32_bf16(af[mt], bf_[nt], acc[mt][nt], 0, 0, 0);
        }
    }

    float bsv[2];
#pragma unroll
    for (int nt = 0; nt < 2; ++nt) bsv[nt] = bp[o0 + wn * 32 + nt * 16 + n16];

    __syncthreads();
    float* Tf = (float*)smem;                    // [64 o][132]
#pragma unroll
    for (int mt = 0; mt < 4; ++mt)
#pragma unroll
        for (int nt = 0; nt < 2; ++nt) {
            int ol = wn * 32 + nt * 16 + n16;
#pragma unroll
            for (int r = 0; r < 4; ++r) {
                int nl = wm * 64 + mt * 16 + quad * 4 + r;
                Tf[ol * 132 + nl] = acc[mt][nt][r] + bsv[nt];
            }
        }
    __syncthreads();
    const int bb = m0 >> 12;
    const int n0 = m0 & (NN - 1);
    const int ro = tid >> 2;                     // 0..63
    const int cc = (tid & 3) * 32;
    const size_t obase = ((size_t)bb * CC_ + o0 + ro) * NN + n0 + cc;
#pragma unroll
    for (int i = 0; i < 8; ++i) {
        float4 v  = *(const float4*)&Tf[ro * 132 + cc + i * 4];
        float4 x4 = *(const float4*)&x[obase + i * 4];
        v.x += x4.x; v.y += x4.y; v.z += x4.z; v.w += x4.w;
        *(float4*)&out[obase + i * 4] = v;
    }
}

extern "C" void kernel_launch(void* const* d_in, const int* in_sizes, int n_in,
                              void* d_out, int out_size, void* d_ws, size_t ws_size,
                              hipStream_t stream) {
    const float* x        = (const float*)d_in[0];
    const float* gn_scale = (const float*)d_in[1];
    const float* gn_bias  = (const float*)d_in[2];
    const float* wq = (const float*)d_in[3];
    const float* bq = (const float*)d_in[4];
    const float* wk = (const float*)d_in[5];
    const float* bk = (const float*)d_in[6];
    const float* wv = (const float*)d_in[7];
    const float* bv = (const float*)d_in[8];
    const float* wp = (const float*)d_in[9];
    const float* bp = (const float*)d_in[10];
    float* outp = (float*)d_out;

    const size_t TENS = (size_t)BB * CC_ * NN;       // 4,194,304 elements
    ushort_t* hT    = (ushort_t*)d_ws;               // bf16 [B][N][C]
    ushort_t* qT    = hT    + TENS;
    ushort_t* kT    = qT    + TENS;
    ushort_t* vB    = kT    + TENS;                  // bf16 [B][C][N]
    ushort_t* attnT = vB    + TENS;                  // bf16 [B][N][C]
    ushort_t* opart = attnT + TENS;                  // bf16 [B][NCH][C][N]
    ushort_t* wqkv  = opart + (size_t)NCH * TENS;    // bf16 [1536][512]
    ushort_t* wpb   = wqkv  + (size_t)1536 * 512;    // bf16 [512][512]
    float*    lpart = (float*)(wpb + (size_t)512 * 512);  // [B][NCH][NN]
    float*    mv    = lpart + (size_t)BB * NCH * NN;      // 128 floats

    wprep<<<1024, 256, 0, stream>>>(wq, wk, wv, wp, wqkv, wpb);
    gn_stats<<<BB * GG, 256, 0, stream>>>(x, mv);
    gn_apply_t<<<dim3(NN / 64, CC_ / 64, BB), 256, 0, stream>>>(x, gn_scale, gn_bias, mv, hT);

    conv_qkv<<<dim3(BB * NN / 128, 1536 / 128), 256, 0, stream>>>(
        hT, wqkv, bq, bk, bv, qT, kT, vB);

    flash_attn6<<<dim3(NN / 128, NCH, BB), 512, 0, stream>>>(qT, kT, vB, opart, lpart);
    combine<<<dim3(NN / 64, CC_ / 64, BB), 256, 0, stream>>>(opart, lpart, attnT);

    conv_proj<<<dim3(BB * NN / 128, CC_ / 64), 256, 0, stream>>>(attnT, wpb, bp, x, outp);
}